// Round 8
// baseline (340.072 us; speedup 1.0000x reference)
//
#include <hip/hip_runtime.h>
#include <hip/hip_bf16.h>

#define BB  4
#define HH  128
#define WW  128
#define CC  192
#define NHH 6
#define KDD 32
#define NTOT (BB*HH*WW*CC)   // 12582912
#define SCALING 0.17677669529663687f
#define WMAT_ELE (12*6*64*8)   // 36864 bf16 elements per matrix, fragment order

typedef __hip_bfloat16 bf16;
typedef short bf16x8 __attribute__((ext_vector_type(8)));
typedef unsigned short ushortx4 __attribute__((ext_vector_type(4)));
typedef float floatx4 __attribute__((ext_vector_type(4)));

__device__ __forceinline__ float b2f(bf16 v) { return __bfloat162float(v); }
__device__ __forceinline__ bf16  f2b(float v) { return __float2bfloat16(v); }
__device__ __forceinline__ unsigned short f2bs(float f) {
  union { bf16 b; unsigned short u; } c; c.b = __float2bfloat16(f); return c.u;
}
__device__ __forceinline__ float s2f(short s) {
  union { unsigned u; float f; } c;
  c.u = ((unsigned)(unsigned short)s) << 16; return c.f;
}

// ---------------- K0: weight prep — fp32 W -> bf16 fragment-order Wt --------
// Wt[mat][nt][kc][lane][j] = W[kc*32 + (lane>>4)*8 + j][nt*16 + (lane&15)]
// (mat order: Wq | Wk*SCALING | Wv | Wo). This makes (a) LDS staging a pure
// linear lane-contiguous copy and (b) ds_read_b128 of a fragment = base +
// lane*16B -> bank-conflict-free with zero swizzle.
__global__ __launch_bounds__(256) void prep_kernel(
    const float* __restrict__ Wq, const float* __restrict__ Wk,
    const float* __restrict__ Wv, const float* __restrict__ Wo,
    unsigned short* __restrict__ Wt) {
  const int idx = blockIdx.x * 256 + threadIdx.x;   // 4*12*6*64 = 18432
  if (idx >= 4 * 12 * 6 * 64) return;
  const int lane = idx & 63;
  int rest = idx >> 6;
  const int kc = rest % 6; rest /= 6;
  const int nt = rest % 12;
  const int mat = rest / 12;
  const int r16 = lane & 15, quad = lane >> 4;
  const float* W = (mat == 0) ? Wq : (mat == 1) ? Wk : (mat == 2) ? Wv : Wo;
  const float sc = (mat == 1) ? SCALING : 1.f;
  bf16x8 t;
  #pragma unroll
  for (int j = 0; j < 8; ++j)
    t[j] = (short)f2bs(W[(kc * 32 + quad * 8 + j) * CC + nt * 16 + r16] * sc);
  *reinterpret_cast<bf16x8*>(&Wt[(size_t)idx * 8]) = t;
}

// ---------------- K1: QKV projection via MFMA, W staged in LDS --------------
__global__ __launch_bounds__(256) void qkv_mfma(
    const float* __restrict__ x, const unsigned short* __restrict__ Wt,
    const float* __restrict__ bq, const float* __restrict__ bk,
    const float* __restrict__ bv,
    bf16* __restrict__ q, bf16* __restrict__ k, bf16* __restrict__ v) {
  __shared__ __align__(16) unsigned short Wlds[18432];   // 36 KB: 6nt x 6kc x 64 x 8
  const int tid = threadIdx.x;
  const int l = tid & 63;
  const int r16 = l & 15, quad = l >> 4;
  const int row0 = blockIdx.x * 128 + (tid >> 6) * 32;   // wave covers 32 rows
  const floatx4 zero = {0.f, 0.f, 0.f, 0.f};
  bf16x8 a[2][6];
  #pragma unroll
  for (int rs = 0; rs < 2; ++rs) {
    const float* xrow = x + (row0 + rs * 16 + r16) * CC;
    #pragma unroll
    for (int kc = 0; kc < 6; ++kc) {
      const float4* p = reinterpret_cast<const float4*>(xrow + kc * 32 + quad * 8);
      float4 u0 = p[0], u1 = p[1];
      bf16x8 t;
      t[0]=f2bs(u0.x); t[1]=f2bs(u0.y); t[2]=f2bs(u0.z); t[3]=f2bs(u0.w);
      t[4]=f2bs(u1.x); t[5]=f2bs(u1.y); t[6]=f2bs(u1.z); t[7]=f2bs(u1.w);
      a[rs][kc] = t;
    }
  }
  for (int mat = 0; mat < 3; ++mat) {
    const unsigned short* Wm = Wt + mat * WMAT_ELE;
    bf16* outp = (mat == 0) ? q : (mat == 1) ? k : v;
    const float* bias = (mat == 0) ? bq : (mat == 1) ? bk : bv;
    const float bscale = (mat == 1) ? SCALING : 1.f;
    for (int hf = 0; hf < 2; ++hf) {
      __syncthreads();   // previous half fully consumed before overwrite
      #pragma unroll
      for (int c = 0; c < 9; ++c) {          // 36 KB = 256 thr x 9 x 16 B
        const int ci = c * 256 + tid;
        *reinterpret_cast<bf16x8*>(&Wlds[ci * 8]) =
            *reinterpret_cast<const bf16x8*>(&Wm[hf * 18432 + ci * 8]);
      }
      __syncthreads();
      #pragma unroll
      for (int ntl = 0; ntl < 6; ++ntl) {
        const int nt = hf * 6 + ntl;
        bf16x8 wfr[6];
        #pragma unroll
        for (int kc = 0; kc < 6; ++kc)
          wfr[kc] = *reinterpret_cast<const bf16x8*>(
              &Wlds[((ntl * 6 + kc) * 64 + l) * 8]);
        floatx4 acc0 = zero, acc1 = zero;
        #pragma unroll
        for (int kc = 0; kc < 6; ++kc) {
          acc0 = __builtin_amdgcn_mfma_f32_16x16x32_bf16(wfr[kc], a[0][kc], acc0, 0, 0, 0);
          acc1 = __builtin_amdgcn_mfma_f32_16x16x32_bf16(wfr[kc], a[1][kc], acc1, 0, 0, 0);
        }
        const int col0 = nt * 16 + quad * 4;
        const float4 b4 = *reinterpret_cast<const float4*>(bias + col0);
        ushortx4 s0, s1;
        s0[0] = f2bs(acc0[0] + b4.x * bscale);
        s0[1] = f2bs(acc0[1] + b4.y * bscale);
        s0[2] = f2bs(acc0[2] + b4.z * bscale);
        s0[3] = f2bs(acc0[3] + b4.w * bscale);
        s1[0] = f2bs(acc1[0] + b4.x * bscale);
        s1[1] = f2bs(acc1[1] + b4.y * bscale);
        s1[2] = f2bs(acc1[2] + b4.z * bscale);
        s1[3] = f2bs(acc1[3] + b4.w * bscale);
        *reinterpret_cast<ushortx4*>(&outp[(row0 + r16) * CC + col0]) = s0;
        *reinterpret_cast<ushortx4*>(&outp[(row0 + 16 + r16) * CC + col0]) = s1;
      }
    }
  }
}

// ---------------- K2: depthwise 5x5 conv (LEPE), LDS-tiled ------------------
// v4: two rounds proved the scheduler re-serializes >~6 in-flight global
// loads regardless of launch_bounds (VGPR pinned at 64). Make latency
// tolerance STRUCTURAL: stage a 12x132x8ch bf16 patch (25 KB, zero-padded
// halo -> no bounds checks in compute) with 7 coalesced batchable loads per
// thread, then 100 conflict-free ds_read_b128 (lane-contiguous 16B, all
// compile-time immediate offsets). Block: 8 h-rows x 128 w x 8 ch; each
// thread: 4 output rows. Tap loop outer -> each kw pair loaded once
// (uniform -> scalar). Same tap order as before -> bit-identical.
__global__ __launch_bounds__(256) void lepe_kernel(
    const bf16* __restrict__ v, const float* __restrict__ kw,
    const float* __restrict__ kb, float* __restrict__ lepe) {
  __shared__ __align__(16) unsigned short patch[12 * 132 * 8];   // 25344 B
  const int tid = threadIdx.x;
  const int cg = blockIdx.x % 24;            // channel group (8 ch)
  const int hb = (blockIdx.x / 24) % 16;     // h tile (8 rows)
  const int b  = blockIdx.x / (24 * 16);
  const int c0 = cg * 8;
  const int h0 = hb * 8;
  const bf16x8 vzero = {0, 0, 0, 0, 0, 0, 0, 0};
  // stage 12 rows x 132 cols x 8 ch (halo rows/cols zero-filled)
  for (int i = tid; i < 12 * 132; i += 256) {
    const int row = i / 132, col = i % 132;
    const int gh = h0 + row - 2, gw = col - 2;
    bf16x8 t = vzero;
    if ((unsigned)gh < HH && (unsigned)gw < WW)
      t = *reinterpret_cast<const bf16x8*>(
          v + ((b * HH + gh) * WW + gw) * CC + c0);
    *reinterpret_cast<bf16x8*>(&patch[i * 8]) = t;
  }
  __syncthreads();
  const int wo = tid & 127;                  // output col
  const int r0 = (tid >> 7) * 4;             // first of 4 output rows
  float acc[4][8];
  {
    const float4* kbp = reinterpret_cast<const float4*>(kb + c0);
    float4 b0 = kbp[0], b1 = kbp[1];
    #pragma unroll
    for (int j = 0; j < 4; ++j) {
      acc[j][0]=b0.x; acc[j][1]=b0.y; acc[j][2]=b0.z; acc[j][3]=b0.w;
      acc[j][4]=b1.x; acc[j][5]=b1.y; acc[j][6]=b1.z; acc[j][7]=b1.w;
    }
  }
  const unsigned short* pbase = &patch[(r0 * 132 + wo) * 8];
  for (int kh = 0; kh < 5; ++kh) {
    #pragma unroll
    for (int kwi = 0; kwi < 5; ++kwi) {
      const float4* kp = reinterpret_cast<const float4*>(
          kw + (kh * 5 + kwi) * CC + c0);
      float4 k0 = kp[0], k1 = kp[1];
      #pragma unroll
      for (int j = 0; j < 4; ++j) {
        bf16x8 t = *reinterpret_cast<const bf16x8*>(
            pbase + ((j + kh) * 132 + kwi) * 8);
        acc[j][0] = fmaf(s2f(t[0]), k0.x, acc[j][0]);
        acc[j][1] = fmaf(s2f(t[1]), k0.y, acc[j][1]);
        acc[j][2] = fmaf(s2f(t[2]), k0.z, acc[j][2]);
        acc[j][3] = fmaf(s2f(t[3]), k0.w, acc[j][3]);
        acc[j][4] = fmaf(s2f(t[4]), k1.x, acc[j][4]);
        acc[j][5] = fmaf(s2f(t[5]), k1.y, acc[j][5]);
        acc[j][6] = fmaf(s2f(t[6]), k1.z, acc[j][6]);
        acc[j][7] = fmaf(s2f(t[7]), k1.w, acc[j][7]);
      }
    }
  }
  #pragma unroll
  for (int j = 0; j < 4; ++j) {
    float4* op = reinterpret_cast<float4*>(
        lepe + ((b * HH + h0 + r0 + j) * WW + wo) * CC + c0);
    op[0] = make_float4(acc[j][0], acc[j][1], acc[j][2], acc[j][3]);
    op[1] = make_float4(acc[j][4], acc[j][5], acc[j][6], acc[j][7]);
  }
}

// ---------------- K3/K4: MFMA attention (row or column axis) ----------------
__global__ __launch_bounds__(64) void attn_mfma_kernel(
    const bf16* __restrict__ qg, const bf16* __restrict__ kg,
    bf16* vbuf, const float* __restrict__ mask,
    const float* __restrict__ lepeadd, const int rstride, const int is_col) {
  __shared__ unsigned short P[16 * 136];
  const int bx = blockIdx.x;
  const int n = bx % NHH;
  const int p = (bx / NHH) % 128;
  const int b = bx / (NHH * 128);
  const int base = is_col ? ((b * HH * WW + p) * CC + n * KDD)
                          : (((b * HH + p) * WW) * CC + n * KDD);
  const int l = threadIdx.x;
  const int r16 = l & 15, quad = l >> 4;
  const float* mbase = mask + n * 128 * 128;
  const floatx4 zero = {0.f, 0.f, 0.f, 0.f};
  const short* vs = (const short*)vbuf;

  bf16x8 kf[8];
  #pragma unroll
  for (int ni = 0; ni < 8; ++ni) {
    kf[ni] = *reinterpret_cast<const bf16x8*>(
        kg + base + (ni * 16 + r16) * rstride + quad * 8);
  }
  bf16x8 vf[4][2];
  #pragma unroll
  for (int s = 0; s < 4; ++s) {
    #pragma unroll
    for (int nj = 0; nj < 2; ++nj) {
      bf16x8 t;
      #pragma unroll
      for (int j = 0; j < 8; ++j) {
        const int key = s * 32 + quad * 8 + j;
        t[j] = vs[base + key * rstride + nj * 16 + r16];
      }
      vf[s][nj] = t;
    }
  }

  for (int mi = 0; mi < 8; ++mi) {
    bf16x8 qf = *reinterpret_cast<const bf16x8*>(
        qg + base + (mi * 16 + r16) * rstride + quad * 8);
    floatx4 S[8];
    #pragma unroll
    for (int ni = 0; ni < 8; ++ni)
      S[ni] = __builtin_amdgcn_mfma_f32_16x16x32_bf16(qf, kf[ni], zero, 0, 0, 0);
    #pragma unroll
    for (int ni = 0; ni < 8; ++ni)
      #pragma unroll
      for (int i = 0; i < 4; ++i)
        S[ni][i] += mbase[(mi * 16 + quad * 4 + i) * 128 + ni * 16 + r16];
    float linv[4], mrow[4];
    #pragma unroll
    for (int i = 0; i < 4; ++i) {
      float m = S[0][i];
      #pragma unroll
      for (int ni = 1; ni < 8; ++ni) m = fmaxf(m, S[ni][i]);
      m = fmaxf(m, __shfl_xor(m, 1));
      m = fmaxf(m, __shfl_xor(m, 2));
      m = fmaxf(m, __shfl_xor(m, 4));
      m = fmaxf(m, __shfl_xor(m, 8));
      mrow[i] = m;
    }
    #pragma unroll
    for (int i = 0; i < 4; ++i) {
      float lsum = 0.f;
      #pragma unroll
      for (int ni = 0; ni < 8; ++ni) {
        const float pv = __expf(S[ni][i] - mrow[i]);
        S[ni][i] = pv;
        lsum += pv;
      }
      lsum += __shfl_xor(lsum, 1);
      lsum += __shfl_xor(lsum, 2);
      lsum += __shfl_xor(lsum, 4);
      lsum += __shfl_xor(lsum, 8);
      linv[i] = 1.f / lsum;
    }
    #pragma unroll
    for (int ni = 0; ni < 8; ++ni)
      #pragma unroll
      for (int i = 0; i < 4; ++i)
        P[(quad * 4 + i) * 136 + ni * 16 + r16] = f2bs(S[ni][i] * linv[i]);
    floatx4 O[2] = {zero, zero};
    #pragma unroll
    for (int s = 0; s < 4; ++s) {
      bf16x8 pf = *reinterpret_cast<const bf16x8*>(
          &P[r16 * 136 + s * 32 + quad * 8]);
      #pragma unroll
      for (int nj = 0; nj < 2; ++nj)
        O[nj] = __builtin_amdgcn_mfma_f32_16x16x32_bf16(pf, vf[s][nj], O[nj], 0, 0, 0);
    }
    #pragma unroll
    for (int nj = 0; nj < 2; ++nj)
      #pragma unroll
      for (int i = 0; i < 4; ++i) {
        const int addr = base + (mi * 16 + quad * 4 + i) * rstride + nj * 16 + r16;
        float val = O[nj][i];
        if (lepeadd) val += lepeadd[addr];
        vbuf[addr] = f2b(val);
      }
  }
}

// ---------------- K5: output projection via MFMA, Wo staged in LDS ----------
__global__ __launch_bounds__(256) void proj_mfma(
    const bf16* __restrict__ pre, const unsigned short* __restrict__ Wto,
    const float* __restrict__ bo, float* __restrict__ out) {
  __shared__ __align__(16) unsigned short Wlds[18432];   // 36 KB
  const int tid = threadIdx.x;
  const int l = tid & 63;
  const int r16 = l & 15, quad = l >> 4;
  const int row0 = blockIdx.x * 128 + (tid >> 6) * 32;
  const floatx4 zero = {0.f, 0.f, 0.f, 0.f};
  bf16x8 a[2][6];
  #pragma unroll
  for (int rs = 0; rs < 2; ++rs)
    #pragma unroll
    for (int kc = 0; kc < 6; ++kc)
      a[rs][kc] = *reinterpret_cast<const bf16x8*>(
          pre + (row0 + rs * 16 + r16) * CC + kc * 32 + quad * 8);
  for (int hf = 0; hf < 2; ++hf) {
    __syncthreads();
    #pragma unroll
    for (int c = 0; c < 9; ++c) {
      const int ci = c * 256 + tid;
      *reinterpret_cast<bf16x8*>(&Wlds[ci * 8]) =
          *reinterpret_cast<const bf16x8*>(&Wto[hf * 18432 + ci * 8]);
    }
    __syncthreads();
    #pragma unroll
    for (int ntl = 0; ntl < 6; ++ntl) {
      const int nt = hf * 6 + ntl;
      bf16x8 wfr[6];
      #pragma unroll
      for (int kc = 0; kc < 6; ++kc)
        wfr[kc] = *reinterpret_cast<const bf16x8*>(
            &Wlds[((ntl * 6 + kc) * 64 + l) * 8]);
      floatx4 acc0 = zero, acc1 = zero;
      #pragma unroll
      for (int kc = 0; kc < 6; ++kc) {
        acc0 = __builtin_amdgcn_mfma_f32_16x16x32_bf16(wfr[kc], a[0][kc], acc0, 0, 0, 0);
        acc1 = __builtin_amdgcn_mfma_f32_16x16x32_bf16(wfr[kc], a[1][kc], acc1, 0, 0, 0);
      }
      const int col0 = nt * 16 + quad * 4;
      const float4 b4 = *reinterpret_cast<const float4*>(bo + col0);
      float4 s0 = make_float4(acc0[0] + b4.x, acc0[1] + b4.y,
                              acc0[2] + b4.z, acc0[3] + b4.w);
      float4 s1 = make_float4(acc1[0] + b4.x, acc1[1] + b4.y,
                              acc1[2] + b4.z, acc1[3] + b4.w);
      *reinterpret_cast<float4*>(&out[(row0 + r16) * CC + col0]) = s0;
      *reinterpret_cast<float4*>(&out[(row0 + 16 + r16) * CC + col0]) = s1;
    }
  }
}

extern "C" void kernel_launch(void* const* d_in, const int* in_sizes, int n_in,
                              void* d_out, int out_size, void* d_ws, size_t ws_size,
                              hipStream_t stream) {
  const float* x      = (const float*)d_in[0];
  const float* mask_h = (const float*)d_in[1];
  const float* mask_w = (const float*)d_in[2];
  const float* Wq = (const float*)d_in[3];
  const float* bq = (const float*)d_in[4];
  const float* Wk = (const float*)d_in[5];
  const float* bk = (const float*)d_in[6];
  const float* Wv = (const float*)d_in[7];
  const float* bv = (const float*)d_in[8];
  const float* lw = (const float*)d_in[9];
  const float* lb = (const float*)d_in[10];
  const float* Wo = (const float*)d_in[11];
  const float* bo = (const float*)d_in[12];
  float* out = (float*)d_out;

  // ws: q bf16 | k bf16 | v bf16 (each NTOT) | Wt bf16 4x36864 = 75.8 MB
  bf16* q    = (bf16*)d_ws;
  bf16* kbuf = q + NTOT;
  bf16* v    = kbuf + NTOT;
  unsigned short* Wt = (unsigned short*)(v + NTOT);

  prep_kernel<<<(4*12*6*64 + 255)/256, 256, 0, stream>>>(Wq, Wk, Wv, Wo, Wt);
  qkv_mfma<<<(BB*HH*WW)/128, 256, 0, stream>>>(x, Wt, bq, bk, bv, q, kbuf, v);
  lepe_kernel<<<BB*16*24, 256, 0, stream>>>(v, lw, lb, out);  // out = lepe
  attn_mfma_kernel<<<BB*128*NHH, 64, 0, stream>>>(
      q, kbuf, v, mask_w, nullptr, CC, 0);                  // v := v1
  attn_mfma_kernel<<<BB*128*NHH, 64, 0, stream>>>(
      q, kbuf, v, mask_h, out, WW*CC, 1);                   // v := attn+lepe
  proj_mfma<<<(BB*HH*WW)/128, 256, 0, stream>>>(v, Wt + 3*WMAT_ELE, bo, out);
}

// Round 9
// 307.457 us; speedup vs baseline: 1.1061x; 1.1061x over previous
//
#include <hip/hip_runtime.h>
#include <hip/hip_bf16.h>

#define BB  4
#define HH  128
#define WW  128
#define CC  192
#define NHH 6
#define KDD 32
#define NTOT (BB*HH*WW*CC)   // 12582912
#define SCALING 0.17677669529663687f
#define WMAT_ELE (12*6*64*8)   // 36864 bf16 elements per matrix, fragment order

typedef __hip_bfloat16 bf16;
typedef short bf16x8 __attribute__((ext_vector_type(8)));
typedef unsigned short ushortx4 __attribute__((ext_vector_type(4)));
typedef float floatx4 __attribute__((ext_vector_type(4)));

__device__ __forceinline__ float b2f(bf16 v) { return __bfloat162float(v); }
__device__ __forceinline__ bf16  f2b(float v) { return __float2bfloat16(v); }
__device__ __forceinline__ unsigned short f2bs(float f) {
  union { bf16 b; unsigned short u; } c; c.b = __float2bfloat16(f); return c.u;
}
__device__ __forceinline__ float s2f(short s) {
  union { unsigned u; float f; } c;
  c.u = ((unsigned)(unsigned short)s) << 16; return c.f;
}

// ---------------- K0: weight prep — fp32 W -> bf16 fragment-order Wt --------
// Wt[mat][nt][kc][lane][j] = W[kc*32 + (lane>>4)*8 + j][nt*16 + (lane&15)]
// (mat order: Wq | Wk*SCALING | Wv | Wo). This makes (a) LDS staging a pure
// linear lane-contiguous copy and (b) ds_read_b128 of a fragment = base +
// lane*16B -> bank-conflict-free with zero swizzle.
__global__ __launch_bounds__(256) void prep_kernel(
    const float* __restrict__ Wq, const float* __restrict__ Wk,
    const float* __restrict__ Wv, const float* __restrict__ Wo,
    unsigned short* __restrict__ Wt) {
  const int idx = blockIdx.x * 256 + threadIdx.x;   // 4*12*6*64 = 18432
  if (idx >= 4 * 12 * 6 * 64) return;
  const int lane = idx & 63;
  int rest = idx >> 6;
  const int kc = rest % 6; rest /= 6;
  const int nt = rest % 12;
  const int mat = rest / 12;
  const int r16 = lane & 15, quad = lane >> 4;
  const float* W = (mat == 0) ? Wq : (mat == 1) ? Wk : (mat == 2) ? Wv : Wo;
  const float sc = (mat == 1) ? SCALING : 1.f;
  bf16x8 t;
  #pragma unroll
  for (int j = 0; j < 8; ++j)
    t[j] = (short)f2bs(W[(kc * 32 + quad * 8 + j) * CC + nt * 16 + r16] * sc);
  *reinterpret_cast<bf16x8*>(&Wt[(size_t)idx * 8]) = t;
}

// ---------------- K1: QKV projection via MFMA, W staged in LDS --------------
__global__ __launch_bounds__(256) void qkv_mfma(
    const float* __restrict__ x, const unsigned short* __restrict__ Wt,
    const float* __restrict__ bq, const float* __restrict__ bk,
    const float* __restrict__ bv,
    bf16* __restrict__ q, bf16* __restrict__ k, bf16* __restrict__ v) {
  __shared__ __align__(16) unsigned short Wlds[18432];   // 36 KB: 6nt x 6kc x 64 x 8
  const int tid = threadIdx.x;
  const int l = tid & 63;
  const int r16 = l & 15, quad = l >> 4;
  const int row0 = blockIdx.x * 128 + (tid >> 6) * 32;   // wave covers 32 rows
  const floatx4 zero = {0.f, 0.f, 0.f, 0.f};
  bf16x8 a[2][6];
  #pragma unroll
  for (int rs = 0; rs < 2; ++rs) {
    const float* xrow = x + (row0 + rs * 16 + r16) * CC;
    #pragma unroll
    for (int kc = 0; kc < 6; ++kc) {
      const float4* p = reinterpret_cast<const float4*>(xrow + kc * 32 + quad * 8);
      float4 u0 = p[0], u1 = p[1];
      bf16x8 t;
      t[0]=f2bs(u0.x); t[1]=f2bs(u0.y); t[2]=f2bs(u0.z); t[3]=f2bs(u0.w);
      t[4]=f2bs(u1.x); t[5]=f2bs(u1.y); t[6]=f2bs(u1.z); t[7]=f2bs(u1.w);
      a[rs][kc] = t;
    }
  }
  for (int mat = 0; mat < 3; ++mat) {
    const unsigned short* Wm = Wt + mat * WMAT_ELE;
    bf16* outp = (mat == 0) ? q : (mat == 1) ? k : v;
    const float* bias = (mat == 0) ? bq : (mat == 1) ? bk : bv;
    const float bscale = (mat == 1) ? SCALING : 1.f;
    for (int hf = 0; hf < 2; ++hf) {
      __syncthreads();   // previous half fully consumed before overwrite
      #pragma unroll
      for (int c = 0; c < 9; ++c) {          // 36 KB = 256 thr x 9 x 16 B
        const int ci = c * 256 + tid;
        *reinterpret_cast<bf16x8*>(&Wlds[ci * 8]) =
            *reinterpret_cast<const bf16x8*>(&Wm[hf * 18432 + ci * 8]);
      }
      __syncthreads();
      #pragma unroll
      for (int ntl = 0; ntl < 6; ++ntl) {
        const int nt = hf * 6 + ntl;
        bf16x8 wfr[6];
        #pragma unroll
        for (int kc = 0; kc < 6; ++kc)
          wfr[kc] = *reinterpret_cast<const bf16x8*>(
              &Wlds[((ntl * 6 + kc) * 64 + l) * 8]);
        floatx4 acc0 = zero, acc1 = zero;
        #pragma unroll
        for (int kc = 0; kc < 6; ++kc) {
          acc0 = __builtin_amdgcn_mfma_f32_16x16x32_bf16(wfr[kc], a[0][kc], acc0, 0, 0, 0);
          acc1 = __builtin_amdgcn_mfma_f32_16x16x32_bf16(wfr[kc], a[1][kc], acc1, 0, 0, 0);
        }
        const int col0 = nt * 16 + quad * 4;
        const float4 b4 = *reinterpret_cast<const float4*>(bias + col0);
        ushortx4 s0, s1;
        s0[0] = f2bs(acc0[0] + b4.x * bscale);
        s0[1] = f2bs(acc0[1] + b4.y * bscale);
        s0[2] = f2bs(acc0[2] + b4.z * bscale);
        s0[3] = f2bs(acc0[3] + b4.w * bscale);
        s1[0] = f2bs(acc1[0] + b4.x * bscale);
        s1[1] = f2bs(acc1[1] + b4.y * bscale);
        s1[2] = f2bs(acc1[2] + b4.z * bscale);
        s1[3] = f2bs(acc1[3] + b4.w * bscale);
        *reinterpret_cast<ushortx4*>(&outp[(row0 + r16) * CC + col0]) = s0;
        *reinterpret_cast<ushortx4*>(&outp[(row0 + 16 + r16) * CC + col0]) = s1;
      }
    }
  }
}

// ---------------- K2: depthwise 5x5 conv (LEPE), LDS-tiled + XCD swizzle ----
// v5: v4's staging loads are 16B/lane at stride 384B (8 of 192 ch), so each
// 64B line is 1/4-used per block; the other 3/4 belongs to neighboring cg
// blocks, which (cg fastest-varying, round-robin dispatch) landed on OTHER
// XCDs -> every XCD re-fetched the same lines: 4x line-waste x 1.5x halo =
// 6x over-fetch (FETCH 144MB vs 24MB ideal, measured). Fix: bijective XCD
// swizzle so all 24 cg blocks of one spatial tile have bid%8 == const ->
// same XCD L2 -> each line fetched once, cg neighbors hit in L2.
__global__ __launch_bounds__(256) void lepe_kernel(
    const bf16* __restrict__ v, const float* __restrict__ kw,
    const float* __restrict__ kb, float* __restrict__ lepe) {
  __shared__ __align__(16) unsigned short patch[12 * 132 * 8];   // 25344 B
  const int tid = threadIdx.x;
  // XCD-aware decode: bid%8 selects the tile partition; all cg of a tile
  // share it. 1536 blocks = 8 xcd x (8 tiles x 24 cg).
  const int bid = blockIdx.x;
  const int x8 = bid & 7;
  const int kk = bid >> 3;            // 0..191
  const int cg = kk % 24;             // channel group (8 ch)
  const int tile = (kk / 24) * 8 + x8; // 0..63
  const int hb = tile & 15;           // h tile (8 rows)
  const int b  = tile >> 4;           // batch
  const int c0 = cg * 8;
  const int h0 = hb * 8;
  const bf16x8 vzero = {0, 0, 0, 0, 0, 0, 0, 0};
  // stage 12 rows x 132 cols x 8 ch (halo rows/cols zero-filled)
  for (int i = tid; i < 12 * 132; i += 256) {
    const int row = i / 132, col = i % 132;
    const int gh = h0 + row - 2, gw = col - 2;
    bf16x8 t = vzero;
    if ((unsigned)gh < HH && (unsigned)gw < WW)
      t = *reinterpret_cast<const bf16x8*>(
          v + ((b * HH + gh) * WW + gw) * CC + c0);
    *reinterpret_cast<bf16x8*>(&patch[i * 8]) = t;
  }
  __syncthreads();
  const int wo = tid & 127;                  // output col
  const int r0 = (tid >> 7) * 4;             // first of 4 output rows
  float acc[4][8];
  {
    const float4* kbp = reinterpret_cast<const float4*>(kb + c0);
    float4 b0 = kbp[0], b1 = kbp[1];
    #pragma unroll
    for (int j = 0; j < 4; ++j) {
      acc[j][0]=b0.x; acc[j][1]=b0.y; acc[j][2]=b0.z; acc[j][3]=b0.w;
      acc[j][4]=b1.x; acc[j][5]=b1.y; acc[j][6]=b1.z; acc[j][7]=b1.w;
    }
  }
  const unsigned short* pbase = &patch[(r0 * 132 + wo) * 8];
  for (int kh = 0; kh < 5; ++kh) {
    #pragma unroll
    for (int kwi = 0; kwi < 5; ++kwi) {
      const float4* kp = reinterpret_cast<const float4*>(
          kw + (kh * 5 + kwi) * CC + c0);
      float4 k0 = kp[0], k1 = kp[1];
      #pragma unroll
      for (int j = 0; j < 4; ++j) {
        bf16x8 t = *reinterpret_cast<const bf16x8*>(
            pbase + ((j + kh) * 132 + kwi) * 8);
        acc[j][0] = fmaf(s2f(t[0]), k0.x, acc[j][0]);
        acc[j][1] = fmaf(s2f(t[1]), k0.y, acc[j][1]);
        acc[j][2] = fmaf(s2f(t[2]), k0.z, acc[j][2]);
        acc[j][3] = fmaf(s2f(t[3]), k0.w, acc[j][3]);
        acc[j][4] = fmaf(s2f(t[4]), k1.x, acc[j][4]);
        acc[j][5] = fmaf(s2f(t[5]), k1.y, acc[j][5]);
        acc[j][6] = fmaf(s2f(t[6]), k1.z, acc[j][6]);
        acc[j][7] = fmaf(s2f(t[7]), k1.w, acc[j][7]);
      }
    }
  }
  #pragma unroll
  for (int j = 0; j < 4; ++j) {
    float4* op = reinterpret_cast<float4*>(
        lepe + ((b * HH + h0 + r0 + j) * WW + wo) * CC + c0);
    op[0] = make_float4(acc[j][0], acc[j][1], acc[j][2], acc[j][3]);
    op[1] = make_float4(acc[j][4], acc[j][5], acc[j][6], acc[j][7]);
  }
}

// ---------------- K3/K4: MFMA attention (row or column axis) ----------------
__global__ __launch_bounds__(64) void attn_mfma_kernel(
    const bf16* __restrict__ qg, const bf16* __restrict__ kg,
    bf16* vbuf, const float* __restrict__ mask,
    const float* __restrict__ lepeadd, const int rstride, const int is_col) {
  __shared__ unsigned short P[16 * 136];
  const int bx = blockIdx.x;
  const int n = bx % NHH;
  const int p = (bx / NHH) % 128;
  const int b = bx / (NHH * 128);
  const int base = is_col ? ((b * HH * WW + p) * CC + n * KDD)
                          : (((b * HH + p) * WW) * CC + n * KDD);
  const int l = threadIdx.x;
  const int r16 = l & 15, quad = l >> 4;
  const float* mbase = mask + n * 128 * 128;
  const floatx4 zero = {0.f, 0.f, 0.f, 0.f};
  const short* vs = (const short*)vbuf;

  bf16x8 kf[8];
  #pragma unroll
  for (int ni = 0; ni < 8; ++ni) {
    kf[ni] = *reinterpret_cast<const bf16x8*>(
        kg + base + (ni * 16 + r16) * rstride + quad * 8);
  }
  bf16x8 vf[4][2];
  #pragma unroll
  for (int s = 0; s < 4; ++s) {
    #pragma unroll
    for (int nj = 0; nj < 2; ++nj) {
      bf16x8 t;
      #pragma unroll
      for (int j = 0; j < 8; ++j) {
        const int key = s * 32 + quad * 8 + j;
        t[j] = vs[base + key * rstride + nj * 16 + r16];
      }
      vf[s][nj] = t;
    }
  }

  for (int mi = 0; mi < 8; ++mi) {
    bf16x8 qf = *reinterpret_cast<const bf16x8*>(
        qg + base + (mi * 16 + r16) * rstride + quad * 8);
    floatx4 S[8];
    #pragma unroll
    for (int ni = 0; ni < 8; ++ni)
      S[ni] = __builtin_amdgcn_mfma_f32_16x16x32_bf16(qf, kf[ni], zero, 0, 0, 0);
    #pragma unroll
    for (int ni = 0; ni < 8; ++ni)
      #pragma unroll
      for (int i = 0; i < 4; ++i)
        S[ni][i] += mbase[(mi * 16 + quad * 4 + i) * 128 + ni * 16 + r16];
    float linv[4], mrow[4];
    #pragma unroll
    for (int i = 0; i < 4; ++i) {
      float m = S[0][i];
      #pragma unroll
      for (int ni = 1; ni < 8; ++ni) m = fmaxf(m, S[ni][i]);
      m = fmaxf(m, __shfl_xor(m, 1));
      m = fmaxf(m, __shfl_xor(m, 2));
      m = fmaxf(m, __shfl_xor(m, 4));
      m = fmaxf(m, __shfl_xor(m, 8));
      mrow[i] = m;
    }
    #pragma unroll
    for (int i = 0; i < 4; ++i) {
      float lsum = 0.f;
      #pragma unroll
      for (int ni = 0; ni < 8; ++ni) {
        const float pv = __expf(S[ni][i] - mrow[i]);
        S[ni][i] = pv;
        lsum += pv;
      }
      lsum += __shfl_xor(lsum, 1);
      lsum += __shfl_xor(lsum, 2);
      lsum += __shfl_xor(lsum, 4);
      lsum += __shfl_xor(lsum, 8);
      linv[i] = 1.f / lsum;
    }
    #pragma unroll
    for (int ni = 0; ni < 8; ++ni)
      #pragma unroll
      for (int i = 0; i < 4; ++i)
        P[(quad * 4 + i) * 136 + ni * 16 + r16] = f2bs(S[ni][i] * linv[i]);
    floatx4 O[2] = {zero, zero};
    #pragma unroll
    for (int s = 0; s < 4; ++s) {
      bf16x8 pf = *reinterpret_cast<const bf16x8*>(
          &P[r16 * 136 + s * 32 + quad * 8]);
      #pragma unroll
      for (int nj = 0; nj < 2; ++nj)
        O[nj] = __builtin_amdgcn_mfma_f32_16x16x32_bf16(pf, vf[s][nj], O[nj], 0, 0, 0);
    }
    #pragma unroll
    for (int nj = 0; nj < 2; ++nj)
      #pragma unroll
      for (int i = 0; i < 4; ++i) {
        const int addr = base + (mi * 16 + quad * 4 + i) * rstride + nj * 16 + r16;
        float val = O[nj][i];
        if (lepeadd) val += lepeadd[addr];
        vbuf[addr] = f2b(val);
      }
  }
}

// ---------------- K5: output projection via MFMA, Wo staged in LDS ----------
__global__ __launch_bounds__(256) void proj_mfma(
    const bf16* __restrict__ pre, const unsigned short* __restrict__ Wto,
    const float* __restrict__ bo, float* __restrict__ out) {
  __shared__ __align__(16) unsigned short Wlds[18432];   // 36 KB
  const int tid = threadIdx.x;
  const int l = tid & 63;
  const int r16 = l & 15, quad = l >> 4;
  const int row0 = blockIdx.x * 128 + (tid >> 6) * 32;
  const floatx4 zero = {0.f, 0.f, 0.f, 0.f};
  bf16x8 a[2][6];
  #pragma unroll
  for (int rs = 0; rs < 2; ++rs)
    #pragma unroll
    for (int kc = 0; kc < 6; ++kc)
      a[rs][kc] = *reinterpret_cast<const bf16x8*>(
          pre + (row0 + rs * 16 + r16) * CC + kc * 32 + quad * 8);
  for (int hf = 0; hf < 2; ++hf) {
    __syncthreads();
    #pragma unroll
    for (int c = 0; c < 9; ++c) {
      const int ci = c * 256 + tid;
      *reinterpret_cast<bf16x8*>(&Wlds[ci * 8]) =
          *reinterpret_cast<const bf16x8*>(&Wto[hf * 18432 + ci * 8]);
    }
    __syncthreads();
    #pragma unroll
    for (int ntl = 0; ntl < 6; ++ntl) {
      const int nt = hf * 6 + ntl;
      bf16x8 wfr[6];
      #pragma unroll
      for (int kc = 0; kc < 6; ++kc)
        wfr[kc] = *reinterpret_cast<const bf16x8*>(
            &Wlds[((ntl * 6 + kc) * 64 + l) * 8]);
      floatx4 acc0 = zero, acc1 = zero;
      #pragma unroll
      for (int kc = 0; kc < 6; ++kc) {
        acc0 = __builtin_amdgcn_mfma_f32_16x16x32_bf16(wfr[kc], a[0][kc], acc0, 0, 0, 0);
        acc1 = __builtin_amdgcn_mfma_f32_16x16x32_bf16(wfr[kc], a[1][kc], acc1, 0, 0, 0);
      }
      const int col0 = nt * 16 + quad * 4;
      const float4 b4 = *reinterpret_cast<const float4*>(bo + col0);
      float4 s0 = make_float4(acc0[0] + b4.x, acc0[1] + b4.y,
                              acc0[2] + b4.z, acc0[3] + b4.w);
      float4 s1 = make_float4(acc1[0] + b4.x, acc1[1] + b4.y,
                              acc1[2] + b4.z, acc1[3] + b4.w);
      *reinterpret_cast<float4*>(&out[(row0 + r16) * CC + col0]) = s0;
      *reinterpret_cast<float4*>(&out[(row0 + 16 + r16) * CC + col0]) = s1;
    }
  }
}

extern "C" void kernel_launch(void* const* d_in, const int* in_sizes, int n_in,
                              void* d_out, int out_size, void* d_ws, size_t ws_size,
                              hipStream_t stream) {
  const float* x      = (const float*)d_in[0];
  const float* mask_h = (const float*)d_in[1];
  const float* mask_w = (const float*)d_in[2];
  const float* Wq = (const float*)d_in[3];
  const float* bq = (const float*)d_in[4];
  const float* Wk = (const float*)d_in[5];
  const float* bk = (const float*)d_in[6];
  const float* Wv = (const float*)d_in[7];
  const float* bv = (const float*)d_in[8];
  const float* lw = (const float*)d_in[9];
  const float* lb = (const float*)d_in[10];
  const float* Wo = (const float*)d_in[11];
  const float* bo = (const float*)d_in[12];
  float* out = (float*)d_out;

  // ws: q bf16 | k bf16 | v bf16 (each NTOT) | Wt bf16 4x36864 = 75.8 MB
  bf16* q    = (bf16*)d_ws;
  bf16* kbuf = q + NTOT;
  bf16* v    = kbuf + NTOT;
  unsigned short* Wt = (unsigned short*)(v + NTOT);

  prep_kernel<<<(4*12*6*64 + 255)/256, 256, 0, stream>>>(Wq, Wk, Wv, Wo, Wt);
  qkv_mfma<<<(BB*HH*WW)/128, 256, 0, stream>>>(x, Wt, bq, bk, bv, q, kbuf, v);
  lepe_kernel<<<BB*16*24, 256, 0, stream>>>(v, lw, lb, out);  // out = lepe
  attn_mfma_kernel<<<BB*128*NHH, 64, 0, stream>>>(
      q, kbuf, v, mask_w, nullptr, CC, 0);                  // v := v1
  attn_mfma_kernel<<<BB*128*NHH, 64, 0, stream>>>(
      q, kbuf, v, mask_h, out, WW*CC, 1);                   // v := attn+lepe
  proj_mfma<<<(BB*HH*WW)/128, 256, 0, stream>>>(v, Wt + 3*WMAT_ELE, bo, out);
}

// Round 10
// 281.146 us; speedup vs baseline: 1.2096x; 1.0936x over previous
//
#include <hip/hip_runtime.h>
#include <hip/hip_bf16.h>

#define BB  4
#define HH  128
#define WW  128
#define CC  192
#define NHH 6
#define KDD 32
#define NTOT (BB*HH*WW*CC)   // 12582912
#define SCALING 0.17677669529663687f
#define WMAT_ELE (12*6*64*8)   // 36864 bf16 elements per matrix, fragment order

typedef __hip_bfloat16 bf16;
typedef short bf16x8 __attribute__((ext_vector_type(8)));
typedef unsigned short ushortx4 __attribute__((ext_vector_type(4)));
typedef float floatx4 __attribute__((ext_vector_type(4)));

__device__ __forceinline__ float b2f(bf16 v) { return __bfloat162float(v); }
__device__ __forceinline__ bf16  f2b(float v) { return __float2bfloat16(v); }
__device__ __forceinline__ unsigned short f2bs(float f) {
  union { bf16 b; unsigned short u; } c; c.b = __float2bfloat16(f); return c.u;
}
__device__ __forceinline__ float s2f(short s) {
  union { unsigned u; float f; } c;
  c.u = ((unsigned)(unsigned short)s) << 16; return c.f;
}

// ---------------- K0: weight prep — fp32 W -> bf16 fragment-order Wt --------
__global__ __launch_bounds__(256) void prep_kernel(
    const float* __restrict__ Wq, const float* __restrict__ Wk,
    const float* __restrict__ Wv, const float* __restrict__ Wo,
    unsigned short* __restrict__ Wt) {
  const int idx = blockIdx.x * 256 + threadIdx.x;   // 4*12*6*64 = 18432
  if (idx >= 4 * 12 * 6 * 64) return;
  const int lane = idx & 63;
  int rest = idx >> 6;
  const int kc = rest % 6; rest /= 6;
  const int nt = rest % 12;
  const int mat = rest / 12;
  const int r16 = lane & 15, quad = lane >> 4;
  const float* W = (mat == 0) ? Wq : (mat == 1) ? Wk : (mat == 2) ? Wv : Wo;
  const float sc = (mat == 1) ? SCALING : 1.f;
  bf16x8 t;
  #pragma unroll
  for (int j = 0; j < 8; ++j)
    t[j] = (short)f2bs(W[(kc * 32 + quad * 8 + j) * CC + nt * 16 + r16] * sc);
  *reinterpret_cast<bf16x8*>(&Wt[(size_t)idx * 8]) = t;
}

// ---------------- K1: QKV projection via MFMA, W staged in LDS --------------
__global__ __launch_bounds__(256) void qkv_mfma(
    const float* __restrict__ x, const unsigned short* __restrict__ Wt,
    const float* __restrict__ bq, const float* __restrict__ bk,
    const float* __restrict__ bv,
    bf16* __restrict__ q, bf16* __restrict__ k, bf16* __restrict__ v) {
  __shared__ __align__(16) unsigned short Wlds[18432];   // 36 KB
  const int tid = threadIdx.x;
  const int l = tid & 63;
  const int r16 = l & 15, quad = l >> 4;
  const int row0 = blockIdx.x * 128 + (tid >> 6) * 32;
  const floatx4 zero = {0.f, 0.f, 0.f, 0.f};
  bf16x8 a[2][6];
  #pragma unroll
  for (int rs = 0; rs < 2; ++rs) {
    const float* xrow = x + (row0 + rs * 16 + r16) * CC;
    #pragma unroll
    for (int kc = 0; kc < 6; ++kc) {
      const float4* p = reinterpret_cast<const float4*>(xrow + kc * 32 + quad * 8);
      float4 u0 = p[0], u1 = p[1];
      bf16x8 t;
      t[0]=f2bs(u0.x); t[1]=f2bs(u0.y); t[2]=f2bs(u0.z); t[3]=f2bs(u0.w);
      t[4]=f2bs(u1.x); t[5]=f2bs(u1.y); t[6]=f2bs(u1.z); t[7]=f2bs(u1.w);
      a[rs][kc] = t;
    }
  }
  for (int mat = 0; mat < 3; ++mat) {
    const unsigned short* Wm = Wt + mat * WMAT_ELE;
    bf16* outp = (mat == 0) ? q : (mat == 1) ? k : v;
    const float* bias = (mat == 0) ? bq : (mat == 1) ? bk : bv;
    const float bscale = (mat == 1) ? SCALING : 1.f;
    for (int hf = 0; hf < 2; ++hf) {
      __syncthreads();
      #pragma unroll
      for (int c = 0; c < 9; ++c) {
        const int ci = c * 256 + tid;
        *reinterpret_cast<bf16x8*>(&Wlds[ci * 8]) =
            *reinterpret_cast<const bf16x8*>(&Wm[hf * 18432 + ci * 8]);
      }
      __syncthreads();
      #pragma unroll
      for (int ntl = 0; ntl < 6; ++ntl) {
        const int nt = hf * 6 + ntl;
        bf16x8 wfr[6];
        #pragma unroll
        for (int kc = 0; kc < 6; ++kc)
          wfr[kc] = *reinterpret_cast<const bf16x8*>(
              &Wlds[((ntl * 6 + kc) * 64 + l) * 8]);
        floatx4 acc0 = zero, acc1 = zero;
        #pragma unroll
        for (int kc = 0; kc < 6; ++kc) {
          acc0 = __builtin_amdgcn_mfma_f32_16x16x32_bf16(wfr[kc], a[0][kc], acc0, 0, 0, 0);
          acc1 = __builtin_amdgcn_mfma_f32_16x16x32_bf16(wfr[kc], a[1][kc], acc1, 0, 0, 0);
        }
        const int col0 = nt * 16 + quad * 4;
        const float4 b4 = *reinterpret_cast<const float4*>(bias + col0);
        ushortx4 s0, s1;
        s0[0] = f2bs(acc0[0] + b4.x * bscale);
        s0[1] = f2bs(acc0[1] + b4.y * bscale);
        s0[2] = f2bs(acc0[2] + b4.z * bscale);
        s0[3] = f2bs(acc0[3] + b4.w * bscale);
        s1[0] = f2bs(acc1[0] + b4.x * bscale);
        s1[1] = f2bs(acc1[1] + b4.y * bscale);
        s1[2] = f2bs(acc1[2] + b4.z * bscale);
        s1[3] = f2bs(acc1[3] + b4.w * bscale);
        *reinterpret_cast<ushortx4*>(&outp[(row0 + r16) * CC + col0]) = s0;
        *reinterpret_cast<ushortx4*>(&outp[(row0 + 16 + r16) * CC + col0]) = s1;
      }
    }
  }
}

// ---------------- K2: depthwise 5x5 conv (LEPE), LDS-tiled + XCD swizzle ----
__global__ __launch_bounds__(256) void lepe_kernel(
    const bf16* __restrict__ v, const float* __restrict__ kw,
    const float* __restrict__ kb, float* __restrict__ lepe) {
  __shared__ __align__(16) unsigned short patch[12 * 132 * 8];   // 25344 B
  const int tid = threadIdx.x;
  const int bid = blockIdx.x;
  const int x8 = bid & 7;
  const int kk = bid >> 3;            // 0..191
  const int cg = kk % 24;             // channel group (8 ch)
  const int tile = (kk / 24) * 8 + x8; // 0..63
  const int hb = tile & 15;           // h tile (8 rows)
  const int b  = tile >> 4;           // batch
  const int c0 = cg * 8;
  const int h0 = hb * 8;
  const bf16x8 vzero = {0, 0, 0, 0, 0, 0, 0, 0};
  for (int i = tid; i < 12 * 132; i += 256) {
    const int row = i / 132, col = i % 132;
    const int gh = h0 + row - 2, gw = col - 2;
    bf16x8 t = vzero;
    if ((unsigned)gh < HH && (unsigned)gw < WW)
      t = *reinterpret_cast<const bf16x8*>(
          v + ((b * HH + gh) * WW + gw) * CC + c0);
    *reinterpret_cast<bf16x8*>(&patch[i * 8]) = t;
  }
  __syncthreads();
  const int wo = tid & 127;
  const int r0 = (tid >> 7) * 4;
  float acc[4][8];
  {
    const float4* kbp = reinterpret_cast<const float4*>(kb + c0);
    float4 b0 = kbp[0], b1 = kbp[1];
    #pragma unroll
    for (int j = 0; j < 4; ++j) {
      acc[j][0]=b0.x; acc[j][1]=b0.y; acc[j][2]=b0.z; acc[j][3]=b0.w;
      acc[j][4]=b1.x; acc[j][5]=b1.y; acc[j][6]=b1.z; acc[j][7]=b1.w;
    }
  }
  const unsigned short* pbase = &patch[(r0 * 132 + wo) * 8];
  for (int kh = 0; kh < 5; ++kh) {
    #pragma unroll
    for (int kwi = 0; kwi < 5; ++kwi) {
      const float4* kp = reinterpret_cast<const float4*>(
          kw + (kh * 5 + kwi) * CC + c0);
      float4 k0 = kp[0], k1 = kp[1];
      #pragma unroll
      for (int j = 0; j < 4; ++j) {
        bf16x8 t = *reinterpret_cast<const bf16x8*>(
            pbase + ((j + kh) * 132 + kwi) * 8);
        acc[j][0] = fmaf(s2f(t[0]), k0.x, acc[j][0]);
        acc[j][1] = fmaf(s2f(t[1]), k0.y, acc[j][1]);
        acc[j][2] = fmaf(s2f(t[2]), k0.z, acc[j][2]);
        acc[j][3] = fmaf(s2f(t[3]), k0.w, acc[j][3]);
        acc[j][4] = fmaf(s2f(t[4]), k1.x, acc[j][4]);
        acc[j][5] = fmaf(s2f(t[5]), k1.y, acc[j][5]);
        acc[j][6] = fmaf(s2f(t[6]), k1.z, acc[j][6]);
        acc[j][7] = fmaf(s2f(t[7]), k1.w, acc[j][7]);
      }
    }
  }
  #pragma unroll
  for (int j = 0; j < 4; ++j) {
    float4* op = reinterpret_cast<float4*>(
        lepe + ((b * HH + h0 + r0 + j) * WW + wo) * CC + c0);
    op[0] = make_float4(acc[j][0], acc[j][1], acc[j][2], acc[j][3]);
    op[1] = make_float4(acc[j][4], acc[j][5], acc[j][6], acc[j][7]);
  }
}

// ---------------- K3/K4: MFMA attention, 4-wave block + LDS K/V -------------
// v2: was 1 wave/block, latency-bound (Occ 27%, MfmaUtil 3.9%): per-thread
// 64 scalar GLOBAL loads for the V-transpose gather + per-wave redundant K.
// Now: 256-thr block per (b,p,n). K and V cooperatively staged into LDS in
// MFMA fragment order (K: aligned b128 writes; V: one-time u16 transpose
// scatter). Waves read fragments as conflict-free lane-contiguous
// ds_read_b128. Each wave handles 2 of the 8 mi tiles; per-wave P buffer
// (no barriers beyond the staging sync). XCD swizzle groups all 6 heads of
// a (b,p) onto one XCD (heads share 128B lines in the col pass).
__global__ __launch_bounds__(256) void attn_mfma_kernel(
    const bf16* __restrict__ qg, const bf16* __restrict__ kg,
    bf16* vbuf, const float* __restrict__ mask,
    const float* __restrict__ lepeadd, const int rstride, const int is_col) {
  __shared__ __align__(16) unsigned short Kf[8 * 64 * 8];   // 8 KB frag-order
  __shared__ __align__(16) unsigned short Vf[8 * 64 * 8];   // 8 KB frag-order
  __shared__ unsigned short P[4 * 16 * 136];                // per-wave P
  const int bid = blockIdx.x;
  const int x8 = bid & 7;
  const int kk = bid >> 3;                  // 0..383
  const int n = kk % NHH;
  const int g = x8 * 64 + kk / NHH;         // (b,p) group, xcd-contiguous
  const int p = g & 127, b = g >> 7;
  const int base = is_col ? ((b * HH * WW + p) * CC + n * KDD)
                          : (((b * HH + p) * WW) * CC + n * KDD);
  const int tid = threadIdx.x;
  const int l = tid & 63, w = tid >> 6;
  const int r16 = l & 15, quad = l >> 4;
  const float* mbase = mask + n * 128 * 128;
  const floatx4 zero = {0.f, 0.f, 0.f, 0.f};
  const unsigned short* vg = (const unsigned short*)vbuf;

  // ---- cooperative staging: 512 chunks of 16B each for K and V ----
  #pragma unroll
  for (int c = 0; c < 2; ++c) {
    const int chunk = c * 256 + tid;
    const int key = chunk >> 2, q4 = chunk & 3;
    const int gaddr = base + key * rstride + q4 * 8;
    bf16x8 tk = *reinterpret_cast<const bf16x8*>(kg + gaddr);
    bf16x8 tv = *reinterpret_cast<const bf16x8*>(vg + gaddr);
    // K frag-order: frag ni=key>>4, lane = q4*16 + (key&15), elems j=0..7
    *reinterpret_cast<bf16x8*>(
        &Kf[(((key >> 4) * 4 + q4) * 16 + (key & 15)) * 8]) = tk;
    // V transpose scatter: frag (s,nj), lane = hi*16 + (ch&15), elem j
    const int s = key >> 5, hi = (key >> 3) & 3, j = key & 7;
    #pragma unroll
    for (int m = 0; m < 8; ++m) {
      const int ch = q4 * 8 + m;
      const int nj = ch >> 4, rr = ch & 15;
      Vf[((s * 2 + nj) * 64 + hi * 16 + rr) * 8 + j] = (unsigned short)tv[m];
    }
  }
  __syncthreads();

  unsigned short* Pw = &P[w * 2176];
  #pragma unroll
  for (int t2 = 0; t2 < 2; ++t2) {
    const int mi = w * 2 + t2;
    bf16x8 qf = *reinterpret_cast<const bf16x8*>(
        qg + base + (mi * 16 + r16) * rstride + quad * 8);
    floatx4 S[8];
    #pragma unroll
    for (int ni = 0; ni < 8; ++ni) {
      bf16x8 kfr = *reinterpret_cast<const bf16x8*>(&Kf[(ni * 64 + l) * 8]);
      S[ni] = __builtin_amdgcn_mfma_f32_16x16x32_bf16(qf, kfr, zero, 0, 0, 0);
    }
    #pragma unroll
    for (int ni = 0; ni < 8; ++ni)
      #pragma unroll
      for (int i = 0; i < 4; ++i)
        S[ni][i] += mbase[(mi * 16 + quad * 4 + i) * 128 + ni * 16 + r16];
    float linv[4], mrow[4];
    #pragma unroll
    for (int i = 0; i < 4; ++i) {
      float m = S[0][i];
      #pragma unroll
      for (int ni = 1; ni < 8; ++ni) m = fmaxf(m, S[ni][i]);
      m = fmaxf(m, __shfl_xor(m, 1));
      m = fmaxf(m, __shfl_xor(m, 2));
      m = fmaxf(m, __shfl_xor(m, 4));
      m = fmaxf(m, __shfl_xor(m, 8));
      mrow[i] = m;
    }
    #pragma unroll
    for (int i = 0; i < 4; ++i) {
      float lsum = 0.f;
      #pragma unroll
      for (int ni = 0; ni < 8; ++ni) {
        const float pv = __expf(S[ni][i] - mrow[i]);
        S[ni][i] = pv;
        lsum += pv;
      }
      lsum += __shfl_xor(lsum, 1);
      lsum += __shfl_xor(lsum, 2);
      lsum += __shfl_xor(lsum, 4);
      lsum += __shfl_xor(lsum, 8);
      linv[i] = 1.f / lsum;
    }
    #pragma unroll
    for (int ni = 0; ni < 8; ++ni)
      #pragma unroll
      for (int i = 0; i < 4; ++i)
        Pw[(quad * 4 + i) * 136 + ni * 16 + r16] = f2bs(S[ni][i] * linv[i]);
    floatx4 O[2] = {zero, zero};
    #pragma unroll
    for (int s = 0; s < 4; ++s) {
      bf16x8 pf = *reinterpret_cast<const bf16x8*>(
          &Pw[r16 * 136 + s * 32 + quad * 8]);
      #pragma unroll
      for (int nj = 0; nj < 2; ++nj) {
        bf16x8 vfr = *reinterpret_cast<const bf16x8*>(
            &Vf[((s * 2 + nj) * 64 + l) * 8]);
        O[nj] = __builtin_amdgcn_mfma_f32_16x16x32_bf16(pf, vfr, O[nj], 0, 0, 0);
      }
    }
    #pragma unroll
    for (int nj = 0; nj < 2; ++nj)
      #pragma unroll
      for (int i = 0; i < 4; ++i) {
        const int addr = base + (mi * 16 + quad * 4 + i) * rstride + nj * 16 + r16;
        float val = O[nj][i];
        if (lepeadd) val += lepeadd[addr];
        vbuf[addr] = f2b(val);
      }
  }
}

// ---------------- K5: output projection via MFMA, Wo staged in LDS ----------
__global__ __launch_bounds__(256) void proj_mfma(
    const bf16* __restrict__ pre, const unsigned short* __restrict__ Wto,
    const float* __restrict__ bo, float* __restrict__ out) {
  __shared__ __align__(16) unsigned short Wlds[18432];   // 36 KB
  const int tid = threadIdx.x;
  const int l = tid & 63;
  const int r16 = l & 15, quad = l >> 4;
  const int row0 = blockIdx.x * 128 + (tid >> 6) * 32;
  const floatx4 zero = {0.f, 0.f, 0.f, 0.f};
  bf16x8 a[2][6];
  #pragma unroll
  for (int rs = 0; rs < 2; ++rs)
    #pragma unroll
    for (int kc = 0; kc < 6; ++kc)
      a[rs][kc] = *reinterpret_cast<const bf16x8*>(
          pre + (row0 + rs * 16 + r16) * CC + kc * 32 + quad * 8);
  for (int hf = 0; hf < 2; ++hf) {
    __syncthreads();
    #pragma unroll
    for (int c = 0; c < 9; ++c) {
      const int ci = c * 256 + tid;
      *reinterpret_cast<bf16x8*>(&Wlds[ci * 8]) =
          *reinterpret_cast<const bf16x8*>(&Wto[hf * 18432 + ci * 8]);
    }
    __syncthreads();
    #pragma unroll
    for (int ntl = 0; ntl < 6; ++ntl) {
      const int nt = hf * 6 + ntl;
      bf16x8 wfr[6];
      #pragma unroll
      for (int kc = 0; kc < 6; ++kc)
        wfr[kc] = *reinterpret_cast<const bf16x8*>(
            &Wlds[((ntl * 6 + kc) * 64 + l) * 8]);
      floatx4 acc0 = zero, acc1 = zero;
      #pragma unroll
      for (int kc = 0; kc < 6; ++kc) {
        acc0 = __builtin_amdgcn_mfma_f32_16x16x32_bf16(wfr[kc], a[0][kc], acc0, 0, 0, 0);
        acc1 = __builtin_amdgcn_mfma_f32_16x16x32_bf16(wfr[kc], a[1][kc], acc1, 0, 0, 0);
      }
      const int col0 = nt * 16 + quad * 4;
      const float4 b4 = *reinterpret_cast<const float4*>(bo + col0);
      float4 s0 = make_float4(acc0[0] + b4.x, acc0[1] + b4.y,
                              acc0[2] + b4.z, acc0[3] + b4.w);
      float4 s1 = make_float4(acc1[0] + b4.x, acc1[1] + b4.y,
                              acc1[2] + b4.z, acc1[3] + b4.w);
      *reinterpret_cast<float4*>(&out[(row0 + r16) * CC + col0]) = s0;
      *reinterpret_cast<float4*>(&out[(row0 + 16 + r16) * CC + col0]) = s1;
    }
  }
}

extern "C" void kernel_launch(void* const* d_in, const int* in_sizes, int n_in,
                              void* d_out, int out_size, void* d_ws, size_t ws_size,
                              hipStream_t stream) {
  const float* x      = (const float*)d_in[0];
  const float* mask_h = (const float*)d_in[1];
  const float* mask_w = (const float*)d_in[2];
  const float* Wq = (const float*)d_in[3];
  const float* bq = (const float*)d_in[4];
  const float* Wk = (const float*)d_in[5];
  const float* bk = (const float*)d_in[6];
  const float* Wv = (const float*)d_in[7];
  const float* bv = (const float*)d_in[8];
  const float* lw = (const float*)d_in[9];
  const float* lb = (const float*)d_in[10];
  const float* Wo = (const float*)d_in[11];
  const float* bo = (const float*)d_in[12];
  float* out = (float*)d_out;

  // ws: q bf16 | k bf16 | v bf16 (each NTOT) | Wt bf16 4x36864 = 75.8 MB
  bf16* q    = (bf16*)d_ws;
  bf16* kbuf = q + NTOT;
  bf16* v    = kbuf + NTOT;
  unsigned short* Wt = (unsigned short*)(v + NTOT);

  prep_kernel<<<(4*12*6*64 + 255)/256, 256, 0, stream>>>(Wq, Wk, Wv, Wo, Wt);
  qkv_mfma<<<(BB*HH*WW)/128, 256, 0, stream>>>(x, Wt, bq, bk, bv, q, kbuf, v);
  lepe_kernel<<<BB*16*24, 256, 0, stream>>>(v, lw, lb, out);  // out = lepe
  attn_mfma_kernel<<<BB*128*NHH, 256, 0, stream>>>(
      q, kbuf, v, mask_w, nullptr, CC, 0);                  // v := v1
  attn_mfma_kernel<<<BB*128*NHH, 256, 0, stream>>>(
      q, kbuf, v, mask_h, out, WW*CC, 1);                   // v := attn+lepe
  proj_mfma<<<(BB*HH*WW)/128, 256, 0, stream>>>(v, Wt + 3*WMAT_ELE, bo, out);
}

// Round 11
// 276.447 us; speedup vs baseline: 1.2302x; 1.0170x over previous
//
#include <hip/hip_runtime.h>
#include <hip/hip_bf16.h>

#define BB  4
#define HH  128
#define WW  128
#define CC  192
#define NHH 6
#define KDD 32
#define NTOT (BB*HH*WW*CC)   // 12582912
#define SCALING 0.17677669529663687f
#define WMAT_ELE (12*6*64*8)   // 36864 bf16 elements per matrix, fragment order

typedef __hip_bfloat16 bf16;
typedef short bf16x8 __attribute__((ext_vector_type(8)));
typedef unsigned short ushortx4 __attribute__((ext_vector_type(4)));
typedef float floatx4 __attribute__((ext_vector_type(4)));

__device__ __forceinline__ float b2f(bf16 v) { return __bfloat162float(v); }
__device__ __forceinline__ bf16  f2b(float v) { return __float2bfloat16(v); }
__device__ __forceinline__ unsigned short f2bs(float f) {
  union { bf16 b; unsigned short u; } c; c.b = __float2bfloat16(f); return c.u;
}
__device__ __forceinline__ float s2f(short s) {
  union { unsigned u; float f; } c;
  c.u = ((unsigned)(unsigned short)s) << 16; return c.f;
}

// ---------------- K0: weight prep — fp32 W -> bf16 fragment-order Wt --------
__global__ __launch_bounds__(256) void prep_kernel(
    const float* __restrict__ Wq, const float* __restrict__ Wk,
    const float* __restrict__ Wv, const float* __restrict__ Wo,
    unsigned short* __restrict__ Wt) {
  const int idx = blockIdx.x * 256 + threadIdx.x;   // 4*12*6*64 = 18432
  if (idx >= 4 * 12 * 6 * 64) return;
  const int lane = idx & 63;
  int rest = idx >> 6;
  const int kc = rest % 6; rest /= 6;
  const int nt = rest % 12;
  const int mat = rest / 12;
  const int r16 = lane & 15, quad = lane >> 4;
  const float* W = (mat == 0) ? Wq : (mat == 1) ? Wk : (mat == 2) ? Wv : Wo;
  const float sc = (mat == 1) ? SCALING : 1.f;
  bf16x8 t;
  #pragma unroll
  for (int j = 0; j < 8; ++j)
    t[j] = (short)f2bs(W[(kc * 32 + quad * 8 + j) * CC + nt * 16 + r16] * sc);
  *reinterpret_cast<bf16x8*>(&Wt[(size_t)idx * 8]) = t;
}

// ---------------- K1: QKV projection via MFMA, W staged in LDS --------------
// v6: round-10 counters showed Occupancy 19.7% (512 blocks = 2 blocks/CU,
// grid-limited) with 80%+ idle cycles: the 6 serial stage->barrier->compute
// phases stall all resident waves with no third block to fill the gap.
// Split ROWS (not nt, not mat -> x still read exactly once): 64 rows/block,
// grid 1024, 4 blocks/CU (4x36KB=144KB LDS) -> 16 waves/CU. W-staging L2
// traffic doubles (L3-resident, ~6.5us aggregate - not a limiter).
__global__ __launch_bounds__(256) void qkv_mfma(
    const float* __restrict__ x, const unsigned short* __restrict__ Wt,
    const float* __restrict__ bq, const float* __restrict__ bk,
    const float* __restrict__ bv,
    bf16* __restrict__ q, bf16* __restrict__ k, bf16* __restrict__ v) {
  __shared__ __align__(16) unsigned short Wlds[18432];   // 36 KB
  const int tid = threadIdx.x;
  const int l = tid & 63;
  const int r16 = l & 15, quad = l >> 4;
  const int row0 = blockIdx.x * 64 + (tid >> 6) * 16;   // wave covers 16 rows
  const floatx4 zero = {0.f, 0.f, 0.f, 0.f};
  bf16x8 a[6];
  {
    const float* xrow = x + (row0 + r16) * CC;
    #pragma unroll
    for (int kc = 0; kc < 6; ++kc) {
      const float4* p = reinterpret_cast<const float4*>(xrow + kc * 32 + quad * 8);
      float4 u0 = p[0], u1 = p[1];
      bf16x8 t;
      t[0]=f2bs(u0.x); t[1]=f2bs(u0.y); t[2]=f2bs(u0.z); t[3]=f2bs(u0.w);
      t[4]=f2bs(u1.x); t[5]=f2bs(u1.y); t[6]=f2bs(u1.z); t[7]=f2bs(u1.w);
      a[kc] = t;
    }
  }
  for (int mat = 0; mat < 3; ++mat) {
    const unsigned short* Wm = Wt + mat * WMAT_ELE;
    bf16* outp = (mat == 0) ? q : (mat == 1) ? k : v;
    const float* bias = (mat == 0) ? bq : (mat == 1) ? bk : bv;
    const float bscale = (mat == 1) ? SCALING : 1.f;
    for (int hf = 0; hf < 2; ++hf) {
      __syncthreads();   // previous half fully consumed before overwrite
      #pragma unroll
      for (int c = 0; c < 9; ++c) {          // 36 KB = 256 thr x 9 x 16 B
        const int ci = c * 256 + tid;
        *reinterpret_cast<bf16x8*>(&Wlds[ci * 8]) =
            *reinterpret_cast<const bf16x8*>(&Wm[hf * 18432 + ci * 8]);
      }
      __syncthreads();
      #pragma unroll
      for (int ntl = 0; ntl < 6; ++ntl) {
        const int nt = hf * 6 + ntl;
        bf16x8 wfr[6];
        #pragma unroll
        for (int kc = 0; kc < 6; ++kc)
          wfr[kc] = *reinterpret_cast<const bf16x8*>(
              &Wlds[((ntl * 6 + kc) * 64 + l) * 8]);
        floatx4 acc = zero;
        #pragma unroll
        for (int kc = 0; kc < 6; ++kc)
          acc = __builtin_amdgcn_mfma_f32_16x16x32_bf16(wfr[kc], a[kc], acc, 0, 0, 0);
        const int col0 = nt * 16 + quad * 4;
        const float4 b4 = *reinterpret_cast<const float4*>(bias + col0);
        ushortx4 s0;
        s0[0] = f2bs(acc[0] + b4.x * bscale);
        s0[1] = f2bs(acc[1] + b4.y * bscale);
        s0[2] = f2bs(acc[2] + b4.z * bscale);
        s0[3] = f2bs(acc[3] + b4.w * bscale);
        *reinterpret_cast<ushortx4*>(&outp[(row0 + r16) * CC + col0]) = s0;
      }
    }
  }
}

// ---------------- K2: depthwise 5x5 conv (LEPE), LDS-tiled + XCD swizzle ----
__global__ __launch_bounds__(256) void lepe_kernel(
    const bf16* __restrict__ v, const float* __restrict__ kw,
    const float* __restrict__ kb, float* __restrict__ lepe) {
  __shared__ __align__(16) unsigned short patch[12 * 132 * 8];   // 25344 B
  const int tid = threadIdx.x;
  const int bid = blockIdx.x;
  const int x8 = bid & 7;
  const int kk = bid >> 3;            // 0..191
  const int cg = kk % 24;             // channel group (8 ch)
  const int tile = (kk / 24) * 8 + x8; // 0..63
  const int hb = tile & 15;           // h tile (8 rows)
  const int b  = tile >> 4;           // batch
  const int c0 = cg * 8;
  const int h0 = hb * 8;
  const bf16x8 vzero = {0, 0, 0, 0, 0, 0, 0, 0};
  for (int i = tid; i < 12 * 132; i += 256) {
    const int row = i / 132, col = i % 132;
    const int gh = h0 + row - 2, gw = col - 2;
    bf16x8 t = vzero;
    if ((unsigned)gh < HH && (unsigned)gw < WW)
      t = *reinterpret_cast<const bf16x8*>(
          v + ((b * HH + gh) * WW + gw) * CC + c0);
    *reinterpret_cast<bf16x8*>(&patch[i * 8]) = t;
  }
  __syncthreads();
  const int wo = tid & 127;
  const int r0 = (tid >> 7) * 4;
  float acc[4][8];
  {
    const float4* kbp = reinterpret_cast<const float4*>(kb + c0);
    float4 b0 = kbp[0], b1 = kbp[1];
    #pragma unroll
    for (int j = 0; j < 4; ++j) {
      acc[j][0]=b0.x; acc[j][1]=b0.y; acc[j][2]=b0.z; acc[j][3]=b0.w;
      acc[j][4]=b1.x; acc[j][5]=b1.y; acc[j][6]=b1.z; acc[j][7]=b1.w;
    }
  }
  const unsigned short* pbase = &patch[(r0 * 132 + wo) * 8];
  for (int kh = 0; kh < 5; ++kh) {
    #pragma unroll
    for (int kwi = 0; kwi < 5; ++kwi) {
      const float4* kp = reinterpret_cast<const float4*>(
          kw + (kh * 5 + kwi) * CC + c0);
      float4 k0 = kp[0], k1 = kp[1];
      #pragma unroll
      for (int j = 0; j < 4; ++j) {
        bf16x8 t = *reinterpret_cast<const bf16x8*>(
            pbase + ((j + kh) * 132 + kwi) * 8);
        acc[j][0] = fmaf(s2f(t[0]), k0.x, acc[j][0]);
        acc[j][1] = fmaf(s2f(t[1]), k0.y, acc[j][1]);
        acc[j][2] = fmaf(s2f(t[2]), k0.z, acc[j][2]);
        acc[j][3] = fmaf(s2f(t[3]), k0.w, acc[j][3]);
        acc[j][4] = fmaf(s2f(t[4]), k1.x, acc[j][4]);
        acc[j][5] = fmaf(s2f(t[5]), k1.y, acc[j][5]);
        acc[j][6] = fmaf(s2f(t[6]), k1.z, acc[j][6]);
        acc[j][7] = fmaf(s2f(t[7]), k1.w, acc[j][7]);
      }
    }
  }
  #pragma unroll
  for (int j = 0; j < 4; ++j) {
    float4* op = reinterpret_cast<float4*>(
        lepe + ((b * HH + h0 + r0 + j) * WW + wo) * CC + c0);
    op[0] = make_float4(acc[j][0], acc[j][1], acc[j][2], acc[j][3]);
    op[1] = make_float4(acc[j][4], acc[j][5], acc[j][6], acc[j][7]);
  }
}

// ---------------- K3/K4: MFMA attention, 4-wave block + LDS K/V -------------
__global__ __launch_bounds__(256) void attn_mfma_kernel(
    const bf16* __restrict__ qg, const bf16* __restrict__ kg,
    bf16* vbuf, const float* __restrict__ mask,
    const float* __restrict__ lepeadd, const int rstride, const int is_col) {
  __shared__ __align__(16) unsigned short Kf[8 * 64 * 8];   // 8 KB frag-order
  __shared__ __align__(16) unsigned short Vf[8 * 64 * 8];   // 8 KB frag-order
  __shared__ unsigned short P[4 * 16 * 136];                // per-wave P
  const int bid = blockIdx.x;
  const int x8 = bid & 7;
  const int kk = bid >> 3;                  // 0..383
  const int n = kk % NHH;
  const int g = x8 * 64 + kk / NHH;         // (b,p) group, xcd-contiguous
  const int p = g & 127, b = g >> 7;
  const int base = is_col ? ((b * HH * WW + p) * CC + n * KDD)
                          : (((b * HH + p) * WW) * CC + n * KDD);
  const int tid = threadIdx.x;
  const int l = tid & 63, w = tid >> 6;
  const int r16 = l & 15, quad = l >> 4;
  const float* mbase = mask + n * 128 * 128;
  const floatx4 zero = {0.f, 0.f, 0.f, 0.f};
  const unsigned short* vg = (const unsigned short*)vbuf;

  // ---- cooperative staging: 512 chunks of 16B each for K and V ----
  #pragma unroll
  for (int c = 0; c < 2; ++c) {
    const int chunk = c * 256 + tid;
    const int key = chunk >> 2, q4 = chunk & 3;
    const int gaddr = base + key * rstride + q4 * 8;
    bf16x8 tk = *reinterpret_cast<const bf16x8*>(kg + gaddr);
    bf16x8 tv = *reinterpret_cast<const bf16x8*>(vg + gaddr);
    // K frag-order: frag ni=key>>4, lane = q4*16 + (key&15), elems j=0..7
    *reinterpret_cast<bf16x8*>(
        &Kf[(((key >> 4) * 4 + q4) * 16 + (key & 15)) * 8]) = tk;
    // V transpose scatter: frag (s,nj), lane = hi*16 + (ch&15), elem j
    const int s = key >> 5, hi = (key >> 3) & 3, j = key & 7;
    #pragma unroll
    for (int m = 0; m < 8; ++m) {
      const int ch = q4 * 8 + m;
      const int nj = ch >> 4, rr = ch & 15;
      Vf[((s * 2 + nj) * 64 + hi * 16 + rr) * 8 + j] = (unsigned short)tv[m];
    }
  }
  __syncthreads();

  unsigned short* Pw = &P[w * 2176];
  #pragma unroll
  for (int t2 = 0; t2 < 2; ++t2) {
    const int mi = w * 2 + t2;
    bf16x8 qf = *reinterpret_cast<const bf16x8*>(
        qg + base + (mi * 16 + r16) * rstride + quad * 8);
    floatx4 S[8];
    #pragma unroll
    for (int ni = 0; ni < 8; ++ni) {
      bf16x8 kfr = *reinterpret_cast<const bf16x8*>(&Kf[(ni * 64 + l) * 8]);
      S[ni] = __builtin_amdgcn_mfma_f32_16x16x32_bf16(qf, kfr, zero, 0, 0, 0);
    }
    #pragma unroll
    for (int ni = 0; ni < 8; ++ni)
      #pragma unroll
      for (int i = 0; i < 4; ++i)
        S[ni][i] += mbase[(mi * 16 + quad * 4 + i) * 128 + ni * 16 + r16];
    float linv[4], mrow[4];
    #pragma unroll
    for (int i = 0; i < 4; ++i) {
      float m = S[0][i];
      #pragma unroll
      for (int ni = 1; ni < 8; ++ni) m = fmaxf(m, S[ni][i]);
      m = fmaxf(m, __shfl_xor(m, 1));
      m = fmaxf(m, __shfl_xor(m, 2));
      m = fmaxf(m, __shfl_xor(m, 4));
      m = fmaxf(m, __shfl_xor(m, 8));
      mrow[i] = m;
    }
    #pragma unroll
    for (int i = 0; i < 4; ++i) {
      float lsum = 0.f;
      #pragma unroll
      for (int ni = 0; ni < 8; ++ni) {
        const float pv = __expf(S[ni][i] - mrow[i]);
        S[ni][i] = pv;
        lsum += pv;
      }
      lsum += __shfl_xor(lsum, 1);
      lsum += __shfl_xor(lsum, 2);
      lsum += __shfl_xor(lsum, 4);
      lsum += __shfl_xor(lsum, 8);
      linv[i] = 1.f / lsum;
    }
    #pragma unroll
    for (int ni = 0; ni < 8; ++ni)
      #pragma unroll
      for (int i = 0; i < 4; ++i)
        Pw[(quad * 4 + i) * 136 + ni * 16 + r16] = f2bs(S[ni][i] * linv[i]);
    floatx4 O[2] = {zero, zero};
    #pragma unroll
    for (int s = 0; s < 4; ++s) {
      bf16x8 pf = *reinterpret_cast<const bf16x8*>(
          &Pw[r16 * 136 + s * 32 + quad * 8]);
      #pragma unroll
      for (int nj = 0; nj < 2; ++nj) {
        bf16x8 vfr = *reinterpret_cast<const bf16x8*>(
            &Vf[((s * 2 + nj) * 64 + l) * 8]);
        O[nj] = __builtin_amdgcn_mfma_f32_16x16x32_bf16(pf, vfr, O[nj], 0, 0, 0);
      }
    }
    #pragma unroll
    for (int nj = 0; nj < 2; ++nj)
      #pragma unroll
      for (int i = 0; i < 4; ++i) {
        const int addr = base + (mi * 16 + quad * 4 + i) * rstride + nj * 16 + r16;
        float val = O[nj][i];
        if (lepeadd) val += lepeadd[addr];
        vbuf[addr] = f2b(val);
      }
  }
}

// ---------------- K5: output projection via MFMA, Wo staged in LDS ----------
__global__ __launch_bounds__(256) void proj_mfma(
    const bf16* __restrict__ pre, const unsigned short* __restrict__ Wto,
    const float* __restrict__ bo, float* __restrict__ out) {
  __shared__ __align__(16) unsigned short Wlds[18432];   // 36 KB
  const int tid = threadIdx.x;
  const int l = tid & 63;
  const int r16 = l & 15, quad = l >> 4;
  const int row0 = blockIdx.x * 128 + (tid >> 6) * 32;
  const floatx4 zero = {0.f, 0.f, 0.f, 0.f};
  bf16x8 a[2][6];
  #pragma unroll
  for (int rs = 0; rs < 2; ++rs)
    #pragma unroll
    for (int kc = 0; kc < 6; ++kc)
      a[rs][kc] = *reinterpret_cast<const bf16x8*>(
          pre + (row0 + rs * 16 + r16) * CC + kc * 32 + quad * 8);
  for (int hf = 0; hf < 2; ++hf) {
    __syncthreads();
    #pragma unroll
    for (int c = 0; c < 9; ++c) {
      const int ci = c * 256 + tid;
      *reinterpret_cast<bf16x8*>(&Wlds[ci * 8]) =
          *reinterpret_cast<const bf16x8*>(&Wto[hf * 18432 + ci * 8]);
    }
    __syncthreads();
    #pragma unroll
    for (int ntl = 0; ntl < 6; ++ntl) {
      const int nt = hf * 6 + ntl;
      bf16x8 wfr[6];
      #pragma unroll
      for (int kc = 0; kc < 6; ++kc)
        wfr[kc] = *reinterpret_cast<const bf16x8*>(
            &Wlds[((ntl * 6 + kc) * 64 + l) * 8]);
      floatx4 acc0 = zero, acc1 = zero;
      #pragma unroll
      for (int kc = 0; kc < 6; ++kc) {
        acc0 = __builtin_amdgcn_mfma_f32_16x16x32_bf16(wfr[kc], a[0][kc], acc0, 0, 0, 0);
        acc1 = __builtin_amdgcn_mfma_f32_16x16x32_bf16(wfr[kc], a[1][kc], acc1, 0, 0, 0);
      }
      const int col0 = nt * 16 + quad * 4;
      const float4 b4 = *reinterpret_cast<const float4*>(bo + col0);
      float4 s0 = make_float4(acc0[0] + b4.x, acc0[1] + b4.y,
                              acc0[2] + b4.z, acc0[3] + b4.w);
      float4 s1 = make_float4(acc1[0] + b4.x, acc1[1] + b4.y,
                              acc1[2] + b4.z, acc1[3] + b4.w);
      *reinterpret_cast<float4*>(&out[(row0 + r16) * CC + col0]) = s0;
      *reinterpret_cast<float4*>(&out[(row0 + 16 + r16) * CC + col0]) = s1;
    }
  }
}

extern "C" void kernel_launch(void* const* d_in, const int* in_sizes, int n_in,
                              void* d_out, int out_size, void* d_ws, size_t ws_size,
                              hipStream_t stream) {
  const float* x      = (const float*)d_in[0];
  const float* mask_h = (const float*)d_in[1];
  const float* mask_w = (const float*)d_in[2];
  const float* Wq = (const float*)d_in[3];
  const float* bq = (const float*)d_in[4];
  const float* Wk = (const float*)d_in[5];
  const float* bk = (const float*)d_in[6];
  const float* Wv = (const float*)d_in[7];
  const float* bv = (const float*)d_in[8];
  const float* lw = (const float*)d_in[9];
  const float* lb = (const float*)d_in[10];
  const float* Wo = (const float*)d_in[11];
  const float* bo = (const float*)d_in[12];
  float* out = (float*)d_out;

  // ws: q bf16 | k bf16 | v bf16 (each NTOT) | Wt bf16 4x36864 = 75.8 MB
  bf16* q    = (bf16*)d_ws;
  bf16* kbuf = q + NTOT;
  bf16* v    = kbuf + NTOT;
  unsigned short* Wt = (unsigned short*)(v + NTOT);

  prep_kernel<<<(4*12*6*64 + 255)/256, 256, 0, stream>>>(Wq, Wk, Wv, Wo, Wt);
  qkv_mfma<<<(BB*HH*WW)/64, 256, 0, stream>>>(x, Wt, bq, bk, bv, q, kbuf, v);
  lepe_kernel<<<BB*16*24, 256, 0, stream>>>(v, lw, lb, out);  // out = lepe
  attn_mfma_kernel<<<BB*128*NHH, 256, 0, stream>>>(
      q, kbuf, v, mask_w, nullptr, CC, 0);                  // v := v1
  attn_mfma_kernel<<<BB*128*NHH, 256, 0, stream>>>(
      q, kbuf, v, mask_h, out, WW*CC, 1);                   // v := attn+lepe
  proj_mfma<<<(BB*HH*WW)/128, 256, 0, stream>>>(v, Wt + 3*WMAT_ELE, bo, out);
}

// Round 12
// 275.292 us; speedup vs baseline: 1.2353x; 1.0042x over previous
//
#include <hip/hip_runtime.h>
#include <hip/hip_bf16.h>

#define BB  4
#define HH  128
#define WW  128
#define CC  192
#define NHH 6
#define KDD 32
#define NTOT (BB*HH*WW*CC)   // 12582912
#define SCALING 0.17677669529663687f
#define WMAT_ELE (12*6*64*8)   // 36864 bf16 elements per matrix, fragment order

typedef __hip_bfloat16 bf16;
typedef short bf16x8 __attribute__((ext_vector_type(8)));
typedef unsigned short ushortx4 __attribute__((ext_vector_type(4)));
typedef float floatx4 __attribute__((ext_vector_type(4)));

__device__ __forceinline__ float b2f(bf16 v) { return __bfloat162float(v); }
__device__ __forceinline__ bf16  f2b(float v) { return __float2bfloat16(v); }
__device__ __forceinline__ unsigned short f2bs(float f) {
  union { bf16 b; unsigned short u; } c; c.b = __float2bfloat16(f); return c.u;
}
__device__ __forceinline__ float s2f(short s) {
  union { unsigned u; float f; } c;
  c.u = ((unsigned)(unsigned short)s) << 16; return c.f;
}

// async global->LDS DMA, 16B per lane. LDS dest = uniform base + lane*16.
__device__ __forceinline__ void stage16(const unsigned short* g,
                                        unsigned short* l) {
  __builtin_amdgcn_global_load_lds(
      (const __attribute__((address_space(1))) void*)g,
      (__attribute__((address_space(3))) void*)l, 16, 0, 0);
}

// ---------------- K0: weight prep — fp32 W -> bf16 fragment-order Wt --------
__global__ __launch_bounds__(256) void prep_kernel(
    const float* __restrict__ Wq, const float* __restrict__ Wk,
    const float* __restrict__ Wv, const float* __restrict__ Wo,
    unsigned short* __restrict__ Wt) {
  const int idx = blockIdx.x * 256 + threadIdx.x;   // 4*12*6*64 = 18432
  if (idx >= 4 * 12 * 6 * 64) return;
  const int lane = idx & 63;
  int rest = idx >> 6;
  const int kc = rest % 6; rest /= 6;
  const int nt = rest % 12;
  const int mat = rest / 12;
  const int r16 = lane & 15, quad = lane >> 4;
  const float* W = (mat == 0) ? Wq : (mat == 1) ? Wk : (mat == 2) ? Wv : Wo;
  const float sc = (mat == 1) ? SCALING : 1.f;
  bf16x8 t;
  #pragma unroll
  for (int j = 0; j < 8; ++j)
    t[j] = (short)f2bs(W[(kc * 32 + quad * 8 + j) * CC + nt * 16 + r16] * sc);
  *reinterpret_cast<bf16x8*>(&Wt[(size_t)idx * 8]) = t;
}

// ---------------- K1: QKV projection, double-buffered global_load_lds -------
// v7: round-11 falsified "more TLP fixes it" - the serial stage->barrier->
// compute phase structure exposes full staging latency every phase. Now:
// 2-phase software pipeline (T3 minimum): quarter-matrix buffers (3nt=18KB,
// x2 dbuf = same 36KB), global_load_lds DMA (no VGPR roundtrip, no ds_write
// chain), loads for quarter t+1 ISSUED BEFORE computing quarter t, single
// __syncthreads per phase drains them AFTER ~400cyc of compute.
__global__ __launch_bounds__(256) void qkv_mfma(
    const float* __restrict__ x, const unsigned short* __restrict__ Wt,
    const float* __restrict__ bq, const float* __restrict__ bk,
    const float* __restrict__ bv,
    bf16* __restrict__ q, bf16* __restrict__ k, bf16* __restrict__ v) {
  __shared__ __align__(16) unsigned short Wlds[2][9216];   // 2 x 18 KB
  const int tid = threadIdx.x;
  const int l = tid & 63, w = tid >> 6;
  const int r16 = l & 15, quad = l >> 4;
  const int row0 = blockIdx.x * 64 + w * 16;   // wave covers 16 rows
  const floatx4 zero = {0.f, 0.f, 0.f, 0.f};
  bf16x8 a[6];
  {
    const float* xrow = x + (row0 + r16) * CC;
    #pragma unroll
    for (int kc = 0; kc < 6; ++kc) {
      const float4* p = reinterpret_cast<const float4*>(xrow + kc * 32 + quad * 8);
      float4 u0 = p[0], u1 = p[1];
      bf16x8 t;
      t[0]=f2bs(u0.x); t[1]=f2bs(u0.y); t[2]=f2bs(u0.z); t[3]=f2bs(u0.w);
      t[4]=f2bs(u1.x); t[5]=f2bs(u1.y); t[6]=f2bs(u1.z); t[7]=f2bs(u1.w);
      a[kc] = t;
    }
  }
  // stage quarter ph (mat = ph/4, quarter = ph%4) into dst: 18 segs x 1024B
  #define STAGE_Q(ph, dst)                                                \
    {                                                                     \
      const unsigned short* src_ =                                        \
          Wt + ((ph) >> 2) * WMAT_ELE + ((ph) & 3) * 9216;                \
      for (int seg = w; seg < 18; seg += 4)                               \
        stage16(src_ + seg * 512 + l * 8, &dst[seg * 512]);               \
    }
  STAGE_Q(0, Wlds[0]);
  __syncthreads();   // quarter 0 resident
  for (int ph = 0; ph < 12; ++ph) {
    const int cur = ph & 1;
    if (ph < 11) STAGE_Q(ph + 1, Wlds[cur ^ 1]);   // issue next (async)
    const int mat = ph >> 2, qq = ph & 3;
    bf16* outp = (mat == 0) ? q : (mat == 1) ? k : v;
    const float* bias = (mat == 0) ? bq : (mat == 1) ? bk : bv;
    const float bscale = (mat == 1) ? SCALING : 1.f;
    #pragma unroll
    for (int ntl = 0; ntl < 3; ++ntl) {
      const int nt = qq * 3 + ntl;
      bf16x8 wfr[6];
      #pragma unroll
      for (int kc = 0; kc < 6; ++kc)
        wfr[kc] = *reinterpret_cast<const bf16x8*>(
            &Wlds[cur][(ntl * 6 + kc) * 512 + l * 8]);
      floatx4 acc = zero;
      #pragma unroll
      for (int kc = 0; kc < 6; ++kc)
        acc = __builtin_amdgcn_mfma_f32_16x16x32_bf16(wfr[kc], a[kc], acc, 0, 0, 0);
      const int col0 = nt * 16 + quad * 4;
      const float4 b4 = *reinterpret_cast<const float4*>(bias + col0);
      ushortx4 s0;
      s0[0] = f2bs(acc[0] + b4.x * bscale);
      s0[1] = f2bs(acc[1] + b4.y * bscale);
      s0[2] = f2bs(acc[2] + b4.z * bscale);
      s0[3] = f2bs(acc[3] + b4.w * bscale);
      *reinterpret_cast<ushortx4*>(&outp[(row0 + r16) * CC + col0]) = s0;
    }
    __syncthreads();   // drains next-quarter loads (after compute) + sync
  }
  #undef STAGE_Q
}

// ---------------- K2: depthwise 5x5 conv (LEPE), LDS-tiled + XCD swizzle ----
__global__ __launch_bounds__(256) void lepe_kernel(
    const bf16* __restrict__ v, const float* __restrict__ kw,
    const float* __restrict__ kb, float* __restrict__ lepe) {
  __shared__ __align__(16) unsigned short patch[12 * 132 * 8];   // 25344 B
  const int tid = threadIdx.x;
  const int bid = blockIdx.x;
  const int x8 = bid & 7;
  const int kk = bid >> 3;            // 0..191
  const int cg = kk % 24;             // channel group (8 ch)
  const int tile = (kk / 24) * 8 + x8; // 0..63
  const int hb = tile & 15;           // h tile (8 rows)
  const int b  = tile >> 4;           // batch
  const int c0 = cg * 8;
  const int h0 = hb * 8;
  const bf16x8 vzero = {0, 0, 0, 0, 0, 0, 0, 0};
  for (int i = tid; i < 12 * 132; i += 256) {
    const int row = i / 132, col = i % 132;
    const int gh = h0 + row - 2, gw = col - 2;
    bf16x8 t = vzero;
    if ((unsigned)gh < HH && (unsigned)gw < WW)
      t = *reinterpret_cast<const bf16x8*>(
          v + ((b * HH + gh) * WW + gw) * CC + c0);
    *reinterpret_cast<bf16x8*>(&patch[i * 8]) = t;
  }
  __syncthreads();
  const int wo = tid & 127;
  const int r0 = (tid >> 7) * 4;
  float acc[4][8];
  {
    const float4* kbp = reinterpret_cast<const float4*>(kb + c0);
    float4 b0 = kbp[0], b1 = kbp[1];
    #pragma unroll
    for (int j = 0; j < 4; ++j) {
      acc[j][0]=b0.x; acc[j][1]=b0.y; acc[j][2]=b0.z; acc[j][3]=b0.w;
      acc[j][4]=b1.x; acc[j][5]=b1.y; acc[j][6]=b1.z; acc[j][7]=b1.w;
    }
  }
  const unsigned short* pbase = &patch[(r0 * 132 + wo) * 8];
  for (int kh = 0; kh < 5; ++kh) {
    #pragma unroll
    for (int kwi = 0; kwi < 5; ++kwi) {
      const float4* kp = reinterpret_cast<const float4*>(
          kw + (kh * 5 + kwi) * CC + c0);
      float4 k0 = kp[0], k1 = kp[1];
      #pragma unroll
      for (int j = 0; j < 4; ++j) {
        bf16x8 t = *reinterpret_cast<const bf16x8*>(
            pbase + ((j + kh) * 132 + kwi) * 8);
        acc[j][0] = fmaf(s2f(t[0]), k0.x, acc[j][0]);
        acc[j][1] = fmaf(s2f(t[1]), k0.y, acc[j][1]);
        acc[j][2] = fmaf(s2f(t[2]), k0.z, acc[j][2]);
        acc[j][3] = fmaf(s2f(t[3]), k0.w, acc[j][3]);
        acc[j][4] = fmaf(s2f(t[4]), k1.x, acc[j][4]);
        acc[j][5] = fmaf(s2f(t[5]), k1.y, acc[j][5]);
        acc[j][6] = fmaf(s2f(t[6]), k1.z, acc[j][6]);
        acc[j][7] = fmaf(s2f(t[7]), k1.w, acc[j][7]);
      }
    }
  }
  #pragma unroll
  for (int j = 0; j < 4; ++j) {
    float4* op = reinterpret_cast<float4*>(
        lepe + ((b * HH + h0 + r0 + j) * WW + wo) * CC + c0);
    op[0] = make_float4(acc[j][0], acc[j][1], acc[j][2], acc[j][3]);
    op[1] = make_float4(acc[j][4], acc[j][5], acc[j][6], acc[j][7]);
  }
}

// ---------------- K3/K4: MFMA attention, 4-wave block + LDS K/V -------------
__global__ __launch_bounds__(256) void attn_mfma_kernel(
    const bf16* __restrict__ qg, const bf16* __restrict__ kg,
    bf16* vbuf, const float* __restrict__ mask,
    const float* __restrict__ lepeadd, const int rstride, const int is_col) {
  __shared__ __align__(16) unsigned short Kf[8 * 64 * 8];   // 8 KB frag-order
  __shared__ __align__(16) unsigned short Vf[8 * 64 * 8];   // 8 KB frag-order
  __shared__ unsigned short P[4 * 16 * 136];                // per-wave P
  const int bid = blockIdx.x;
  const int x8 = bid & 7;
  const int kk = bid >> 3;                  // 0..383
  const int n = kk % NHH;
  const int g = x8 * 64 + kk / NHH;         // (b,p) group, xcd-contiguous
  const int p = g & 127, b = g >> 7;
  const int base = is_col ? ((b * HH * WW + p) * CC + n * KDD)
                          : (((b * HH + p) * WW) * CC + n * KDD);
  const int tid = threadIdx.x;
  const int l = tid & 63, w = tid >> 6;
  const int r16 = l & 15, quad = l >> 4;
  const float* mbase = mask + n * 128 * 128;
  const floatx4 zero = {0.f, 0.f, 0.f, 0.f};
  const unsigned short* vg = (const unsigned short*)vbuf;

  // ---- cooperative staging: 512 chunks of 16B each for K and V ----
  #pragma unroll
  for (int c = 0; c < 2; ++c) {
    const int chunk = c * 256 + tid;
    const int key = chunk >> 2, q4 = chunk & 3;
    const int gaddr = base + key * rstride + q4 * 8;
    bf16x8 tk = *reinterpret_cast<const bf16x8*>(kg + gaddr);
    bf16x8 tv = *reinterpret_cast<const bf16x8*>(vg + gaddr);
    // K frag-order: frag ni=key>>4, lane = q4*16 + (key&15), elems j=0..7
    *reinterpret_cast<bf16x8*>(
        &Kf[(((key >> 4) * 4 + q4) * 16 + (key & 15)) * 8]) = tk;
    // V transpose scatter: frag (s,nj), lane = hi*16 + (ch&15), elem j
    const int s = key >> 5, hi = (key >> 3) & 3, j = key & 7;
    #pragma unroll
    for (int m = 0; m < 8; ++m) {
      const int ch = q4 * 8 + m;
      const int nj = ch >> 4, rr = ch & 15;
      Vf[((s * 2 + nj) * 64 + hi * 16 + rr) * 8 + j] = (unsigned short)tv[m];
    }
  }
  __syncthreads();

  unsigned short* Pw = &P[w * 2176];
  #pragma unroll
  for (int t2 = 0; t2 < 2; ++t2) {
    const int mi = w * 2 + t2;
    bf16x8 qf = *reinterpret_cast<const bf16x8*>(
        qg + base + (mi * 16 + r16) * rstride + quad * 8);
    floatx4 S[8];
    #pragma unroll
    for (int ni = 0; ni < 8; ++ni) {
      bf16x8 kfr = *reinterpret_cast<const bf16x8*>(&Kf[(ni * 64 + l) * 8]);
      S[ni] = __builtin_amdgcn_mfma_f32_16x16x32_bf16(qf, kfr, zero, 0, 0, 0);
    }
    #pragma unroll
    for (int ni = 0; ni < 8; ++ni)
      #pragma unroll
      for (int i = 0; i < 4; ++i)
        S[ni][i] += mbase[(mi * 16 + quad * 4 + i) * 128 + ni * 16 + r16];
    float linv[4], mrow[4];
    #pragma unroll
    for (int i = 0; i < 4; ++i) {
      float m = S[0][i];
      #pragma unroll
      for (int ni = 1; ni < 8; ++ni) m = fmaxf(m, S[ni][i]);
      m = fmaxf(m, __shfl_xor(m, 1));
      m = fmaxf(m, __shfl_xor(m, 2));
      m = fmaxf(m, __shfl_xor(m, 4));
      m = fmaxf(m, __shfl_xor(m, 8));
      mrow[i] = m;
    }
    #pragma unroll
    for (int i = 0; i < 4; ++i) {
      float lsum = 0.f;
      #pragma unroll
      for (int ni = 0; ni < 8; ++ni) {
        const float pv = __expf(S[ni][i] - mrow[i]);
        S[ni][i] = pv;
        lsum += pv;
      }
      lsum += __shfl_xor(lsum, 1);
      lsum += __shfl_xor(lsum, 2);
      lsum += __shfl_xor(lsum, 4);
      lsum += __shfl_xor(lsum, 8);
      linv[i] = 1.f / lsum;
    }
    #pragma unroll
    for (int ni = 0; ni < 8; ++ni)
      #pragma unroll
      for (int i = 0; i < 4; ++i)
        Pw[(quad * 4 + i) * 136 + ni * 16 + r16] = f2bs(S[ni][i] * linv[i]);
    floatx4 O[2] = {zero, zero};
    #pragma unroll
    for (int s = 0; s < 4; ++s) {
      bf16x8 pf = *reinterpret_cast<const bf16x8*>(
          &Pw[r16 * 136 + s * 32 + quad * 8]);
      #pragma unroll
      for (int nj = 0; nj < 2; ++nj) {
        bf16x8 vfr = *reinterpret_cast<const bf16x8*>(
            &Vf[((s * 2 + nj) * 64 + l) * 8]);
        O[nj] = __builtin_amdgcn_mfma_f32_16x16x32_bf16(pf, vfr, O[nj], 0, 0, 0);
      }
    }
    #pragma unroll
    for (int nj = 0; nj < 2; ++nj)
      #pragma unroll
      for (int i = 0; i < 4; ++i) {
        const int addr = base + (mi * 16 + quad * 4 + i) * rstride + nj * 16 + r16;
        float val = O[nj][i];
        if (lepeadd) val += lepeadd[addr];
        vbuf[addr] = f2b(val);
      }
  }
}

// ---------------- K5: output projection via MFMA, Wo staged in LDS ----------
__global__ __launch_bounds__(256) void proj_mfma(
    const bf16* __restrict__ pre, const unsigned short* __restrict__ Wto,
    const float* __restrict__ bo, float* __restrict__ out) {
  __shared__ __align__(16) unsigned short Wlds[18432];   // 36 KB
  const int tid = threadIdx.x;
  const int l = tid & 63;
  const int r16 = l & 15, quad = l >> 4;
  const int row0 = blockIdx.x * 128 + (tid >> 6) * 32;
  const floatx4 zero = {0.f, 0.f, 0.f, 0.f};
  bf16x8 a[2][6];
  #pragma unroll
  for (int rs = 0; rs < 2; ++rs)
    #pragma unroll
    for (int kc = 0; kc < 6; ++kc)
      a[rs][kc] = *reinterpret_cast<const bf16x8*>(
          pre + (row0 + rs * 16 + r16) * CC + kc * 32 + quad * 8);
  for (int hf = 0; hf < 2; ++hf) {
    __syncthreads();
    #pragma unroll
    for (int c = 0; c < 9; ++c) {
      const int ci = c * 256 + tid;
      *reinterpret_cast<bf16x8*>(&Wlds[ci * 8]) =
          *reinterpret_cast<const bf16x8*>(&Wto[hf * 18432 + ci * 8]);
    }
    __syncthreads();
    #pragma unroll
    for (int ntl = 0; ntl < 6; ++ntl) {
      const int nt = hf * 6 + ntl;
      bf16x8 wfr[6];
      #pragma unroll
      for (int kc = 0; kc < 6; ++kc)
        wfr[kc] = *reinterpret_cast<const bf16x8*>(
            &Wlds[((ntl * 6 + kc) * 64 + l) * 8]);
      floatx4 acc0 = zero, acc1 = zero;
      #pragma unroll
      for (int kc = 0; kc < 6; ++kc) {
        acc0 = __builtin_amdgcn_mfma_f32_16x16x32_bf16(wfr[kc], a[0][kc], acc0, 0, 0, 0);
        acc1 = __builtin_amdgcn_mfma_f32_16x16x32_bf16(wfr[kc], a[1][kc], acc1, 0, 0, 0);
      }
      const int col0 = nt * 16 + quad * 4;
      const float4 b4 = *reinterpret_cast<const float4*>(bo + col0);
      float4 s0 = make_float4(acc0[0] + b4.x, acc0[1] + b4.y,
                              acc0[2] + b4.z, acc0[3] + b4.w);
      float4 s1 = make_float4(acc1[0] + b4.x, acc1[1] + b4.y,
                              acc1[2] + b4.z, acc1[3] + b4.w);
      *reinterpret_cast<float4*>(&out[(row0 + r16) * CC + col0]) = s0;
      *reinterpret_cast<float4*>(&out[(row0 + 16 + r16) * CC + col0]) = s1;
    }
  }
}

extern "C" void kernel_launch(void* const* d_in, const int* in_sizes, int n_in,
                              void* d_out, int out_size, void* d_ws, size_t ws_size,
                              hipStream_t stream) {
  const float* x      = (const float*)d_in[0];
  const float* mask_h = (const float*)d_in[1];
  const float* mask_w = (const float*)d_in[2];
  const float* Wq = (const float*)d_in[3];
  const float* bq = (const float*)d_in[4];
  const float* Wk = (const float*)d_in[5];
  const float* bk = (const float*)d_in[6];
  const float* Wv = (const float*)d_in[7];
  const float* bv = (const float*)d_in[8];
  const float* lw = (const float*)d_in[9];
  const float* lb = (const float*)d_in[10];
  const float* Wo = (const float*)d_in[11];
  const float* bo = (const float*)d_in[12];
  float* out = (float*)d_out;

  // ws: q bf16 | k bf16 | v bf16 (each NTOT) | Wt bf16 4x36864 = 75.8 MB
  bf16* q    = (bf16*)d_ws;
  bf16* kbuf = q + NTOT;
  bf16* v    = kbuf + NTOT;
  unsigned short* Wt = (unsigned short*)(v + NTOT);

  prep_kernel<<<(4*12*6*64 + 255)/256, 256, 0, stream>>>(Wq, Wk, Wv, Wo, Wt);
  qkv_mfma<<<(BB*HH*WW)/64, 256, 0, stream>>>(x, Wt, bq, bk, bv, q, kbuf, v);
  lepe_kernel<<<BB*16*24, 256, 0, stream>>>(v, lw, lb, out);  // out = lepe
  attn_mfma_kernel<<<BB*128*NHH, 256, 0, stream>>>(
      q, kbuf, v, mask_w, nullptr, CC, 0);                  // v := v1
  attn_mfma_kernel<<<BB*128*NHH, 256, 0, stream>>>(
      q, kbuf, v, mask_h, out, WW*CC, 1);                   // v := attn+lepe
  proj_mfma<<<(BB*HH*WW)/128, 256, 0, stream>>>(v, Wt + 3*WMAT_ELE, bo, out);
}

// Round 13
// 265.372 us; speedup vs baseline: 1.2815x; 1.0374x over previous
//
#include <hip/hip_runtime.h>
#include <hip/hip_bf16.h>

#define BB  4
#define HH  128
#define WW  128
#define CC  192
#define NHH 6
#define KDD 32
#define NTOT (BB*HH*WW*CC)   // 12582912
#define SCALING 0.17677669529663687f
#define WMAT_ELE (12*6*64*8)   // 36864 bf16 elements per matrix, fragment order

typedef __hip_bfloat16 bf16;
typedef short bf16x8 __attribute__((ext_vector_type(8)));
typedef unsigned short ushortx4 __attribute__((ext_vector_type(4)));
typedef float floatx4 __attribute__((ext_vector_type(4)));

__device__ __forceinline__ float b2f(bf16 v) { return __bfloat162float(v); }
__device__ __forceinline__ bf16  f2b(float v) { return __float2bfloat16(v); }
__device__ __forceinline__ unsigned short f2bs(float f) {
  union { bf16 b; unsigned short u; } c; c.b = __float2bfloat16(f); return c.u;
}
__device__ __forceinline__ float s2f(short s) {
  union { unsigned u; float f; } c;
  c.u = ((unsigned)(unsigned short)s) << 16; return c.f;
}

// async global->LDS DMA, 16B per lane. LDS dest = uniform base + lane*16.
__device__ __forceinline__ void stage16(const unsigned short* g,
                                        unsigned short* l) {
  __builtin_amdgcn_global_load_lds(
      (const __attribute__((address_space(1))) void*)g,
      (__attribute__((address_space(3))) void*)l, 16, 0, 0);
}

// ---------------- K0: weight prep — fp32 W -> bf16 fragment-order Wt --------
__global__ __launch_bounds__(256) void prep_kernel(
    const float* __restrict__ Wq, const float* __restrict__ Wk,
    const float* __restrict__ Wv, const float* __restrict__ Wo,
    unsigned short* __restrict__ Wt) {
  const int idx = blockIdx.x * 256 + threadIdx.x;   // 4*12*6*64 = 18432
  if (idx >= 4 * 12 * 6 * 64) return;
  const int lane = idx & 63;
  int rest = idx >> 6;
  const int kc = rest % 6; rest /= 6;
  const int nt = rest % 12;
  const int mat = rest / 12;
  const int r16 = lane & 15, quad = lane >> 4;
  const float* W = (mat == 0) ? Wq : (mat == 1) ? Wk : (mat == 2) ? Wv : Wo;
  const float sc = (mat == 1) ? SCALING : 1.f;
  bf16x8 t;
  #pragma unroll
  for (int j = 0; j < 8; ++j)
    t[j] = (short)f2bs(W[(kc * 32 + quad * 8 + j) * CC + nt * 16 + r16] * sc);
  *reinterpret_cast<bf16x8*>(&Wt[(size_t)idx * 8]) = t;
}

// ---------------- K1: QKV projection, double-buffered global_load_lds -------
__global__ __launch_bounds__(256) void qkv_mfma(
    const float* __restrict__ x, const unsigned short* __restrict__ Wt,
    const float* __restrict__ bq, const float* __restrict__ bk,
    const float* __restrict__ bv,
    bf16* __restrict__ q, bf16* __restrict__ k, bf16* __restrict__ v) {
  __shared__ __align__(16) unsigned short Wlds[2][9216];   // 2 x 18 KB
  const int tid = threadIdx.x;
  const int l = tid & 63, w = tid >> 6;
  const int r16 = l & 15, quad = l >> 4;
  const int row0 = blockIdx.x * 64 + w * 16;   // wave covers 16 rows
  const floatx4 zero = {0.f, 0.f, 0.f, 0.f};
  bf16x8 a[6];
  {
    const float* xrow = x + (row0 + r16) * CC;
    #pragma unroll
    for (int kc = 0; kc < 6; ++kc) {
      const float4* p = reinterpret_cast<const float4*>(xrow + kc * 32 + quad * 8);
      float4 u0 = p[0], u1 = p[1];
      bf16x8 t;
      t[0]=f2bs(u0.x); t[1]=f2bs(u0.y); t[2]=f2bs(u0.z); t[3]=f2bs(u0.w);
      t[4]=f2bs(u1.x); t[5]=f2bs(u1.y); t[6]=f2bs(u1.z); t[7]=f2bs(u1.w);
      a[kc] = t;
    }
  }
  #define STAGE_Q(ph, dst)                                                \
    {                                                                     \
      const unsigned short* src_ =                                        \
          Wt + ((ph) >> 2) * WMAT_ELE + ((ph) & 3) * 9216;                \
      for (int seg = w; seg < 18; seg += 4)                               \
        stage16(src_ + seg * 512 + l * 8, &dst[seg * 512]);               \
    }
  STAGE_Q(0, Wlds[0]);
  __syncthreads();   // quarter 0 resident
  for (int ph = 0; ph < 12; ++ph) {
    const int cur = ph & 1;
    if (ph < 11) STAGE_Q(ph + 1, Wlds[cur ^ 1]);   // issue next (async)
    const int mat = ph >> 2, qq = ph & 3;
    bf16* outp = (mat == 0) ? q : (mat == 1) ? k : v;
    const float* bias = (mat == 0) ? bq : (mat == 1) ? bk : bv;
    const float bscale = (mat == 1) ? SCALING : 1.f;
    #pragma unroll
    for (int ntl = 0; ntl < 3; ++ntl) {
      const int nt = qq * 3 + ntl;
      bf16x8 wfr[6];
      #pragma unroll
      for (int kc = 0; kc < 6; ++kc)
        wfr[kc] = *reinterpret_cast<const bf16x8*>(
            &Wlds[cur][(ntl * 6 + kc) * 512 + l * 8]);
      floatx4 acc = zero;
      #pragma unroll
      for (int kc = 0; kc < 6; ++kc)
        acc = __builtin_amdgcn_mfma_f32_16x16x32_bf16(wfr[kc], a[kc], acc, 0, 0, 0);
      const int col0 = nt * 16 + quad * 4;
      const float4 b4 = *reinterpret_cast<const float4*>(bias + col0);
      ushortx4 s0;
      s0[0] = f2bs(acc[0] + b4.x * bscale);
      s0[1] = f2bs(acc[1] + b4.y * bscale);
      s0[2] = f2bs(acc[2] + b4.z * bscale);
      s0[3] = f2bs(acc[3] + b4.w * bscale);
      *reinterpret_cast<ushortx4*>(&outp[(row0 + r16) * CC + col0]) = s0;
    }
    __syncthreads();   // drains next-quarter loads (after compute) + sync
  }
  #undef STAGE_Q
}

// ---------------- K2: depthwise 5x5 conv (LEPE), LDS-tiled + XCD swizzle ----
__global__ __launch_bounds__(256) void lepe_kernel(
    const bf16* __restrict__ v, const float* __restrict__ kw,
    const float* __restrict__ kb, float* __restrict__ lepe) {
  __shared__ __align__(16) unsigned short patch[12 * 132 * 8];   // 25344 B
  const int tid = threadIdx.x;
  const int bid = blockIdx.x;
  const int x8 = bid & 7;
  const int kk = bid >> 3;            // 0..191
  const int cg = kk % 24;             // channel group (8 ch)
  const int tile = (kk / 24) * 8 + x8; // 0..63
  const int hb = tile & 15;           // h tile (8 rows)
  const int b  = tile >> 4;           // batch
  const int c0 = cg * 8;
  const int h0 = hb * 8;
  const bf16x8 vzero = {0, 0, 0, 0, 0, 0, 0, 0};
  for (int i = tid; i < 12 * 132; i += 256) {
    const int row = i / 132, col = i % 132;
    const int gh = h0 + row - 2, gw = col - 2;
    bf16x8 t = vzero;
    if ((unsigned)gh < HH && (unsigned)gw < WW)
      t = *reinterpret_cast<const bf16x8*>(
          v + ((b * HH + gh) * WW + gw) * CC + c0);
    *reinterpret_cast<bf16x8*>(&patch[i * 8]) = t;
  }
  __syncthreads();
  const int wo = tid & 127;
  const int r0 = (tid >> 7) * 4;
  float acc[4][8];
  {
    const float4* kbp = reinterpret_cast<const float4*>(kb + c0);
    float4 b0 = kbp[0], b1 = kbp[1];
    #pragma unroll
    for (int j = 0; j < 4; ++j) {
      acc[j][0]=b0.x; acc[j][1]=b0.y; acc[j][2]=b0.z; acc[j][3]=b0.w;
      acc[j][4]=b1.x; acc[j][5]=b1.y; acc[j][6]=b1.z; acc[j][7]=b1.w;
    }
  }
  const unsigned short* pbase = &patch[(r0 * 132 + wo) * 8];
  for (int kh = 0; kh < 5; ++kh) {
    #pragma unroll
    for (int kwi = 0; kwi < 5; ++kwi) {
      const float4* kp = reinterpret_cast<const float4*>(
          kw + (kh * 5 + kwi) * CC + c0);
      float4 k0 = kp[0], k1 = kp[1];
      #pragma unroll
      for (int j = 0; j < 4; ++j) {
        bf16x8 t = *reinterpret_cast<const bf16x8*>(
            pbase + ((j + kh) * 132 + kwi) * 8);
        acc[j][0] = fmaf(s2f(t[0]), k0.x, acc[j][0]);
        acc[j][1] = fmaf(s2f(t[1]), k0.y, acc[j][1]);
        acc[j][2] = fmaf(s2f(t[2]), k0.z, acc[j][2]);
        acc[j][3] = fmaf(s2f(t[3]), k0.w, acc[j][3]);
        acc[j][4] = fmaf(s2f(t[4]), k1.x, acc[j][4]);
        acc[j][5] = fmaf(s2f(t[5]), k1.y, acc[j][5]);
        acc[j][6] = fmaf(s2f(t[6]), k1.z, acc[j][6]);
        acc[j][7] = fmaf(s2f(t[7]), k1.w, acc[j][7]);
      }
    }
  }
  #pragma unroll
  for (int j = 0; j < 4; ++j) {
    float4* op = reinterpret_cast<float4*>(
        lepe + ((b * HH + h0 + r0 + j) * WW + wo) * CC + c0);
    op[0] = make_float4(acc[j][0], acc[j][1], acc[j][2], acc[j][3]);
    op[1] = make_float4(acc[j][4], acc[j][5], acc[j][6], acc[j][7]);
  }
}

// ---------------- K3/K4: MFMA attention, 4-wave + preloaded operands --------
// v3 (T14 async-split): round-12 counters (VALUBusy 44%, MfmaUtil 5%, ~3x
// above traffic+compute floor) = stall-bound mi loop. The 32 scalar mask
// loads + q fragment per tile sat mid-chain between QK and softmax. Now ALL
// global operands (q frags x2, 64 mask scalars, pass-2 lepe) are issued
// BEFORE the K/V staging barrier into registers - their latency drains
// under the staging scatter. mi loop = pure LDS/MFMA/VALU.
// __launch_bounds__(256,4): LDS caps at 4 blocks/CU = 4 waves/SIMD anyway,
// so allow the allocator 128 VGPR for the 64 mask registers (round-6 lesson:
// default heuristic would re-serialize the batch).
__global__ __launch_bounds__(256, 4) void attn_mfma_kernel(
    const bf16* __restrict__ qg, const bf16* __restrict__ kg,
    bf16* vbuf, const float* __restrict__ mask,
    const float* __restrict__ lepeadd, const int rstride, const int is_col) {
  __shared__ __align__(16) unsigned short Kf[8 * 64 * 8];   // 8 KB frag-order
  __shared__ __align__(16) unsigned short Vf[8 * 64 * 8];   // 8 KB frag-order
  __shared__ unsigned short P[4 * 16 * 136];                // per-wave P
  const int bid = blockIdx.x;
  const int x8 = bid & 7;
  const int kk = bid >> 3;                  // 0..383
  const int n = kk % NHH;
  const int g = x8 * 64 + kk / NHH;         // (b,p) group, xcd-contiguous
  const int p = g & 127, b = g >> 7;
  const int base = is_col ? ((b * HH * WW + p) * CC + n * KDD)
                          : (((b * HH + p) * WW) * CC + n * KDD);
  const int tid = threadIdx.x;
  const int l = tid & 63, w = tid >> 6;
  const int r16 = l & 15, quad = l >> 4;
  const float* mbase = mask + n * 128 * 128;
  const floatx4 zero = {0.f, 0.f, 0.f, 0.f};
  const unsigned short* vg = (const unsigned short*)vbuf;

  // ---- T14 preload: q fragments + mask tiles for both mi, into regs ----
  bf16x8 qf[2];
  float mk[2][8][4];
  #pragma unroll
  for (int t2 = 0; t2 < 2; ++t2) {
    const int mi = w * 2 + t2;
    qf[t2] = *reinterpret_cast<const bf16x8*>(
        qg + base + (mi * 16 + r16) * rstride + quad * 8);
    #pragma unroll
    for (int ni = 0; ni < 8; ++ni)
      #pragma unroll
      for (int i = 0; i < 4; ++i)
        mk[t2][ni][i] = mbase[(mi * 16 + quad * 4 + i) * 128 + ni * 16 + r16];
  }

  // ---- cooperative staging: 512 chunks of 16B each for K and V ----
  #pragma unroll
  for (int c = 0; c < 2; ++c) {
    const int chunk = c * 256 + tid;
    const int key = chunk >> 2, q4 = chunk & 3;
    const int gaddr = base + key * rstride + q4 * 8;
    bf16x8 tk = *reinterpret_cast<const bf16x8*>(kg + gaddr);
    bf16x8 tv = *reinterpret_cast<const bf16x8*>(vg + gaddr);
    *reinterpret_cast<bf16x8*>(
        &Kf[(((key >> 4) * 4 + q4) * 16 + (key & 15)) * 8]) = tk;
    const int s = key >> 5, hi = (key >> 3) & 3, j = key & 7;
    #pragma unroll
    for (int m = 0; m < 8; ++m) {
      const int ch = q4 * 8 + m;
      const int nj = ch >> 4, rr = ch & 15;
      Vf[((s * 2 + nj) * 64 + hi * 16 + rr) * 8 + j] = (unsigned short)tv[m];
    }
  }
  __syncthreads();

  unsigned short* Pw = &P[w * 2176];
  #pragma unroll
  for (int t2 = 0; t2 < 2; ++t2) {
    const int mi = w * 2 + t2;
    floatx4 S[8];
    #pragma unroll
    for (int ni = 0; ni < 8; ++ni) {
      bf16x8 kfr = *reinterpret_cast<const bf16x8*>(&Kf[(ni * 64 + l) * 8]);
      S[ni] = __builtin_amdgcn_mfma_f32_16x16x32_bf16(qf[t2], kfr, zero, 0, 0, 0);
    }
    #pragma unroll
    for (int ni = 0; ni < 8; ++ni)
      #pragma unroll
      for (int i = 0; i < 4; ++i)
        S[ni][i] += mk[t2][ni][i];
    float linv[4], mrow[4];
    #pragma unroll
    for (int i = 0; i < 4; ++i) {
      float m = S[0][i];
      #pragma unroll
      for (int ni = 1; ni < 8; ++ni) m = fmaxf(m, S[ni][i]);
      m = fmaxf(m, __shfl_xor(m, 1));
      m = fmaxf(m, __shfl_xor(m, 2));
      m = fmaxf(m, __shfl_xor(m, 4));
      m = fmaxf(m, __shfl_xor(m, 8));
      mrow[i] = m;
    }
    #pragma unroll
    for (int i = 0; i < 4; ++i) {
      float lsum = 0.f;
      #pragma unroll
      for (int ni = 0; ni < 8; ++ni) {
        const float pv = __expf(S[ni][i] - mrow[i]);
        S[ni][i] = pv;
        lsum += pv;
      }
      lsum += __shfl_xor(lsum, 1);
      lsum += __shfl_xor(lsum, 2);
      lsum += __shfl_xor(lsum, 4);
      lsum += __shfl_xor(lsum, 8);
      linv[i] = 1.f / lsum;
    }
    #pragma unroll
    for (int ni = 0; ni < 8; ++ni)
      #pragma unroll
      for (int i = 0; i < 4; ++i)
        Pw[(quad * 4 + i) * 136 + ni * 16 + r16] = f2bs(S[ni][i] * linv[i]);
    // hoist pass-2 lepe loads above the PV MFMAs
    float lp[2][4];
    if (lepeadd) {
      #pragma unroll
      for (int nj = 0; nj < 2; ++nj)
        #pragma unroll
        for (int i = 0; i < 4; ++i)
          lp[nj][i] = lepeadd[base + (mi * 16 + quad * 4 + i) * rstride +
                              nj * 16 + r16];
    }
    floatx4 O[2] = {zero, zero};
    #pragma unroll
    for (int s = 0; s < 4; ++s) {
      bf16x8 pf = *reinterpret_cast<const bf16x8*>(
          &Pw[r16 * 136 + s * 32 + quad * 8]);
      #pragma unroll
      for (int nj = 0; nj < 2; ++nj) {
        bf16x8 vfr = *reinterpret_cast<const bf16x8*>(
            &Vf[((s * 2 + nj) * 64 + l) * 8]);
        O[nj] = __builtin_amdgcn_mfma_f32_16x16x32_bf16(pf, vfr, O[nj], 0, 0, 0);
      }
    }
    #pragma unroll
    for (int nj = 0; nj < 2; ++nj)
      #pragma unroll
      for (int i = 0; i < 4; ++i) {
        const int addr = base + (mi * 16 + quad * 4 + i) * rstride + nj * 16 + r16;
        float val = O[nj][i];
        if (lepeadd) val += lp[nj][i];
        vbuf[addr] = f2b(val);
      }
  }
}

// ---------------- K5: output projection via MFMA, Wo staged in LDS ----------
__global__ __launch_bounds__(256) void proj_mfma(
    const bf16* __restrict__ pre, const unsigned short* __restrict__ Wto,
    const float* __restrict__ bo, float* __restrict__ out) {
  __shared__ __align__(16) unsigned short Wlds[18432];   // 36 KB
  const int tid = threadIdx.x;
  const int l = tid & 63;
  const int r16 = l & 15, quad = l >> 4;
  const int row0 = blockIdx.x * 128 + (tid >> 6) * 32;
  const floatx4 zero = {0.f, 0.f, 0.f, 0.f};
  bf16x8 a[2][6];
  #pragma unroll
  for (int rs = 0; rs < 2; ++rs)
    #pragma unroll
    for (int kc = 0; kc < 6; ++kc)
      a[rs][kc] = *reinterpret_cast<const bf16x8*>(
          pre + (row0 + rs * 16 + r16) * CC + kc * 32 + quad * 8);
  for (int hf = 0; hf < 2; ++hf) {
    __syncthreads();
    #pragma unroll
    for (int c = 0; c < 9; ++c) {
      const int ci = c * 256 + tid;
      *reinterpret_cast<bf16x8*>(&Wlds[ci * 8]) =
          *reinterpret_cast<const bf16x8*>(&Wto[hf * 18432 + ci * 8]);
    }
    __syncthreads();
    #pragma unroll
    for (int ntl = 0; ntl < 6; ++ntl) {
      const int nt = hf * 6 + ntl;
      bf16x8 wfr[6];
      #pragma unroll
      for (int kc = 0; kc < 6; ++kc)
        wfr[kc] = *reinterpret_cast<const bf16x8*>(
            &Wlds[((ntl * 6 + kc) * 64 + l) * 8]);
      floatx4 acc0 = zero, acc1 = zero;
      #pragma unroll
      for (int kc = 0; kc < 6; ++kc) {
        acc0 = __builtin_amdgcn_mfma_f32_16x16x32_bf16(wfr[kc], a[0][kc], acc0, 0, 0, 0);
        acc1 = __builtin_amdgcn_mfma_f32_16x16x32_bf16(wfr[kc], a[1][kc], acc1, 0, 0, 0);
      }
      const int col0 = nt * 16 + quad * 4;
      const float4 b4 = *reinterpret_cast<const float4*>(bo + col0);
      float4 s0 = make_float4(acc0[0] + b4.x, acc0[1] + b4.y,
                              acc0[2] + b4.z, acc0[3] + b4.w);
      float4 s1 = make_float4(acc1[0] + b4.x, acc1[1] + b4.y,
                              acc1[2] + b4.z, acc1[3] + b4.w);
      *reinterpret_cast<float4*>(&out[(row0 + r16) * CC + col0]) = s0;
      *reinterpret_cast<float4*>(&out[(row0 + 16 + r16) * CC + col0]) = s1;
    }
  }
}

extern "C" void kernel_launch(void* const* d_in, const int* in_sizes, int n_in,
                              void* d_out, int out_size, void* d_ws, size_t ws_size,
                              hipStream_t stream) {
  const float* x      = (const float*)d_in[0];
  const float* mask_h = (const float*)d_in[1];
  const float* mask_w = (const float*)d_in[2];
  const float* Wq = (const float*)d_in[3];
  const float* bq = (const float*)d_in[4];
  const float* Wk = (const float*)d_in[5];
  const float* bk = (const float*)d_in[6];
  const float* Wv = (const float*)d_in[7];
  const float* bv = (const float*)d_in[8];
  const float* lw = (const float*)d_in[9];
  const float* lb = (const float*)d_in[10];
  const float* Wo = (const float*)d_in[11];
  const float* bo = (const float*)d_in[12];
  float* out = (float*)d_out;

  // ws: q bf16 | k bf16 | v bf16 (each NTOT) | Wt bf16 4x36864 = 75.8 MB
  bf16* q    = (bf16*)d_ws;
  bf16* kbuf = q + NTOT;
  bf16* v    = kbuf + NTOT;
  unsigned short* Wt = (unsigned short*)(v + NTOT);

  prep_kernel<<<(4*12*6*64 + 255)/256, 256, 0, stream>>>(Wq, Wk, Wv, Wo, Wt);
  qkv_mfma<<<(BB*HH*WW)/64, 256, 0, stream>>>(x, Wt, bq, bk, bv, q, kbuf, v);
  lepe_kernel<<<BB*16*24, 256, 0, stream>>>(v, lw, lb, out);  // out = lepe
  attn_mfma_kernel<<<BB*128*NHH, 256, 0, stream>>>(
      q, kbuf, v, mask_w, nullptr, CC, 0);                  // v := v1
  attn_mfma_kernel<<<BB*128*NHH, 256, 0, stream>>>(
      q, kbuf, v, mask_h, out, WW*CC, 1);                   // v := attn+lepe
  proj_mfma<<<(BB*HH*WW)/128, 256, 0, stream>>>(v, Wt + 3*WMAT_ELE, bo, out);
}